// Round 7
// baseline (260.570 us; speedup 1.0000x reference)
//
#include <hip/hip_runtime.h>
#include <math.h>

#define N_GRAPHS 512
#define CAP 5120          // bucket capacity: mean 4096, sigma 64
#define TILE_A 4096       // edges per phase-A workgroup (16/thread)

static inline size_t align_up(size_t v, size_t a) { return (v + a - 1) / a * a; }

// ---- init per-bucket write cursors to region starts -------------------------
__global__ void k_initCursor(int* __restrict__ cursor, int nb) {
    int i = blockIdx.x * blockDim.x + threadIdx.x;
    if (i < nb) cursor[i] = i * CAP;
}

// ---- split x (n x 10) -> xpA (n x 8) + xpB (n x 2) --------------------------
__global__ void k_pad2(const float* __restrict__ x, float4* __restrict__ xpA,
                       float2* __restrict__ xpB, int n) {
    int v = blockIdx.x * 256 + threadIdx.x;
    if (v >= n) return;
    const float* row = x + (size_t)v * 10;
    xpA[2 * (size_t)v]     = make_float4(row[0], row[1], row[2], row[3]);
    xpA[2 * (size_t)v + 1] = make_float4(row[4], row[5], row[6], row[7]);
    xpB[v] = make_float2(row[8], row[9]);
}

// ---- Phase A: partition edges into dst-range buckets ------------------------
__global__ void k_bucketA(const int* __restrict__ src, const int* __restrict__ dst,
                          int* __restrict__ cursor, int* __restrict__ bucketBuf,
                          int ne, int nb) {
    __shared__ int hist[512];
    __shared__ int base[512];
    for (int i = threadIdx.x; i < nb; i += 256) hist[i] = 0;
    __syncthreads();
    int t0 = blockIdx.x * TILE_A + threadIdx.x;
    int s[16], d[16];
#pragma unroll
    for (int k = 0; k < 16; ++k) {
        int e = t0 + k * 256;
        if (e < ne) { s[k] = src[e]; d[k] = dst[e]; }
        else        { s[k] = 0; d[k] = -1; }
    }
#pragma unroll
    for (int k = 0; k < 16; ++k)
        if (d[k] >= 0) atomicAdd(&hist[d[k] >> 8], 1);
    __syncthreads();
    for (int i = threadIdx.x; i < nb; i += 256)
        base[i] = (hist[i] > 0) ? atomicAdd(&cursor[i], hist[i]) : 0;
    __syncthreads();
#pragma unroll
    for (int k = 0; k < 16; ++k)
        if (d[k] >= 0) {
            int b = d[k] >> 8;
            int slot = atomicAdd(&base[b], 1);
            int lim = b * CAP + (CAP - 1);
            if (slot > lim) slot = lim;   // overflow guard (never expected)
            bucketBuf[slot] = (s[k] << 8) | (d[k] & 255);
        }
}

// ---- Phase B: per-bucket counting sort -> csr + packed(beg,deg) + dinv ------
__global__ void k_bucketB(const int* __restrict__ cursor, const int* __restrict__ bucketBuf,
                          int* __restrict__ csr, unsigned* __restrict__ pk,
                          float* __restrict__ dinv, int n) {
    int b = blockIdx.x;
    int beg = b * CAP;
    int cnt = cursor[b] - beg;
    if (cnt > CAP) cnt = CAP;
    __shared__ int hist[256];
    __shared__ int scan[256];
    hist[threadIdx.x] = 0;
    __syncthreads();
    for (int j = threadIdx.x; j < cnt; j += 256)
        atomicAdd(&hist[bucketBuf[beg + j] & 255], 1);
    __syncthreads();
    int v = hist[threadIdx.x];
    scan[threadIdx.x] = v;
    __syncthreads();
    for (int off = 1; off < 256; off <<= 1) {
        int t = (threadIdx.x >= off) ? scan[threadIdx.x - off] : 0;
        __syncthreads();
        scan[threadIdx.x] += t;
        __syncthreads();
    }
    int excl = scan[threadIdx.x] - v;
    int node = (b << 8) + threadIdx.x;
    if (node < n) {
        pk[node] = (unsigned)(beg + excl) | ((unsigned)v << 22);
        float dd = (float)v + 1.0f;
        dinv[node] = 1.0f / sqrtf(dd);
    }
    __syncthreads();
    hist[threadIdx.x] = excl;   // reuse as scatter cursor
    __syncthreads();
    for (int j = threadIdx.x; j < cnt; j += 256) {
        int pkk = bucketBuf[beg + j];
        int slot = atomicAdd(&hist[pkk & 255], 1);
        csr[beg + slot] = pkk >> 8;
    }
}

// ---- gather layer-1, XCD-chunked (chunk0: feats 0-7, chunk1: feats 8-9) -----
__global__ void k_gather1c(const int* __restrict__ csr, const unsigned* __restrict__ pk,
                           const float* __restrict__ dinv,
                           const float4* __restrict__ xpA, const float2* __restrict__ xpB,
                           float4* __restrict__ zA, float2* __restrict__ zB, int n) {
    int chunk = blockIdx.x & 1;
    int v = (blockIdx.x >> 1) * 256 + threadIdx.x;
    if (v >= n) return;
    unsigned p = pk[v];
    int beg = (int)(p & 0x3FFFFFu);
    int end = beg + (int)(p >> 22);
    float dv = dinv[v];
    float iv = dv * dv;
    if (chunk == 0) {
        float4 a0 = make_float4(0.f, 0.f, 0.f, 0.f);
        float4 a1 = make_float4(0.f, 0.f, 0.f, 0.f);
        int j = beg;
        for (; j + 4 <= end; j += 4) {
            int s0 = csr[j], s1 = csr[j + 1], s2 = csr[j + 2], s3 = csr[j + 3];
            float w0 = dinv[s0], w1 = dinv[s1], w2 = dinv[s2], w3 = dinv[s3];
            float4 p00 = xpA[2 * (size_t)s0], p01 = xpA[2 * (size_t)s0 + 1];
            float4 p10 = xpA[2 * (size_t)s1], p11 = xpA[2 * (size_t)s1 + 1];
            float4 p20 = xpA[2 * (size_t)s2], p21 = xpA[2 * (size_t)s2 + 1];
            float4 p30 = xpA[2 * (size_t)s3], p31 = xpA[2 * (size_t)s3 + 1];
            a0.x += w0*p00.x + w1*p10.x + w2*p20.x + w3*p30.x;
            a0.y += w0*p00.y + w1*p10.y + w2*p20.y + w3*p30.y;
            a0.z += w0*p00.z + w1*p10.z + w2*p20.z + w3*p30.z;
            a0.w += w0*p00.w + w1*p10.w + w2*p20.w + w3*p30.w;
            a1.x += w0*p01.x + w1*p11.x + w2*p21.x + w3*p31.x;
            a1.y += w0*p01.y + w1*p11.y + w2*p21.y + w3*p31.y;
            a1.z += w0*p01.z + w1*p11.z + w2*p21.z + w3*p31.z;
            a1.w += w0*p01.w + w1*p11.w + w2*p21.w + w3*p31.w;
        }
        for (; j < end; ++j) {
            int s = csr[j];
            float w = dinv[s];
            float4 p0 = xpA[2 * (size_t)s], p1 = xpA[2 * (size_t)s + 1];
            a0.x += w*p0.x; a0.y += w*p0.y; a0.z += w*p0.z; a0.w += w*p0.w;
            a1.x += w*p1.x; a1.y += w*p1.y; a1.z += w*p1.z; a1.w += w*p1.w;
        }
        float4 x0 = xpA[2 * (size_t)v], x1 = xpA[2 * (size_t)v + 1];
        a0.x = a0.x * dv + iv * x0.x; a0.y = a0.y * dv + iv * x0.y;
        a0.z = a0.z * dv + iv * x0.z; a0.w = a0.w * dv + iv * x0.w;
        a1.x = a1.x * dv + iv * x1.x; a1.y = a1.y * dv + iv * x1.y;
        a1.z = a1.z * dv + iv * x1.z; a1.w = a1.w * dv + iv * x1.w;
        zA[2 * (size_t)v] = a0;
        zA[2 * (size_t)v + 1] = a1;
    } else {
        float2 a = make_float2(0.f, 0.f);
        int j = beg;
        for (; j + 4 <= end; j += 4) {
            int s0 = csr[j], s1 = csr[j + 1], s2 = csr[j + 2], s3 = csr[j + 3];
            float w0 = dinv[s0], w1 = dinv[s1], w2 = dinv[s2], w3 = dinv[s3];
            float2 r0 = xpB[s0], r1 = xpB[s1], r2 = xpB[s2], r3 = xpB[s3];
            a.x += w0*r0.x + w1*r1.x + w2*r2.x + w3*r3.x;
            a.y += w0*r0.y + w1*r1.y + w2*r2.y + w3*r3.y;
        }
        for (; j < end; ++j) {
            int s = csr[j];
            float w = dinv[s];
            float2 r = xpB[s];
            a.x += w * r.x; a.y += w * r.y;
        }
        float2 xv = xpB[v];
        a.x = a.x * dv + iv * xv.x;
        a.y = a.y * dv + iv * xv.y;
        zB[v] = a;
    }
}

// ---- lin: m = relu(z@W1+b1)@W2, written chunk-major mT[4][n][8] -------------
__global__ void k_lin(const float4* __restrict__ zA, const float2* __restrict__ zB,
                      const float* __restrict__ W1, const float* __restrict__ b1,
                      const float* __restrict__ W2, float* __restrict__ mT, int n) {
    __shared__ float W1s[640];
    __shared__ float W2s[2048];
    __shared__ float zt[64 * 12];
    __shared__ float hs[64 * 65];
    for (int i = threadIdx.x; i < 640; i += 256)  W1s[i] = W1[i];
    for (int i = threadIdx.x; i < 2048; i += 256) W2s[i] = W2[i];
    {
        int node = threadIdx.x >> 2, q = threadIdx.x & 3;
        int v = blockIdx.x * 64 + node;
        if (v < n) {
            if (q < 2) {
                float4 r = zA[2 * (size_t)v + q];
                zt[node * 12 + q * 4 + 0] = r.x;
                zt[node * 12 + q * 4 + 1] = r.y;
                zt[node * 12 + q * 4 + 2] = r.z;
                zt[node * 12 + q * 4 + 3] = r.w;
            } else if (q == 2) {
                float2 r = zB[v];
                zt[node * 12 + 8] = r.x;
                zt[node * 12 + 9] = r.y;
            }
        } else if (q == 0) {
#pragma unroll
            for (int k = 0; k < 10; ++k) zt[node * 12 + k] = 0.f;
        }
    }
    __syncthreads();
    {
        int node = threadIdx.x & 63, w = threadIdx.x >> 6;
        float zreg[10];
#pragma unroll
        for (int k = 0; k < 10; ++k) zreg[k] = zt[node * 12 + k];
#pragma unroll
        for (int fq = 0; fq < 16; ++fq) {
            int f = w * 16 + fq;
            float s = b1[f];
#pragma unroll
            for (int k = 0; k < 10; ++k) s += zreg[k] * W1s[k * 64 + f];
            hs[node * 65 + f] = fmaxf(s, 0.f);
        }
    }
    __syncthreads();
    {
        int o = threadIdx.x & 31, nb8 = threadIdx.x >> 5;
        int chunk = o >> 3, within = o & 7;
#pragma unroll
        for (int it = 0; it < 8; ++it) {
            int node = it * 8 + nb8;
            int vv = blockIdx.x * 64 + node;
            if (vv < n) {
                float s = 0.f;
#pragma unroll
                for (int f = 0; f < 64; ++f) s += hs[node * 65 + f] * W2s[f * 32 + o];
                mT[((size_t)chunk * n + vv) * 8 + within] = s;
            }
        }
    }
}

// ---- gather layer-2, XCD-chunked (4 chunks x 8 feats) + relu + pool ---------
__global__ void k_gather2c(const int* __restrict__ csr, const unsigned* __restrict__ pk,
                           const float* __restrict__ dinv, const float* __restrict__ mT,
                           const float* __restrict__ b2, const int* __restrict__ batch,
                           float* __restrict__ pooled, int n) {
    int chunk = blockIdx.x & 3;
    int v = (blockIdx.x >> 2) * 256 + threadIdx.x;
    bool valid = (v < n);
    const float4* mc = (const float4*)mT + (size_t)chunk * n * 2;
    float4 a0 = make_float4(0.f, 0.f, 0.f, 0.f);
    float4 a1 = make_float4(0.f, 0.f, 0.f, 0.f);
    int b = -1;
    if (valid) {
        unsigned p = pk[v];
        int beg = (int)(p & 0x3FFFFFu);
        int end = beg + (int)(p >> 22);
        float dv = dinv[v];
        int j = beg;
        for (; j + 4 <= end; j += 4) {
            int s0 = csr[j], s1 = csr[j + 1], s2 = csr[j + 2], s3 = csr[j + 3];
            float w0 = dinv[s0], w1 = dinv[s1], w2 = dinv[s2], w3 = dinv[s3];
            float4 p00 = mc[2 * (size_t)s0], p01 = mc[2 * (size_t)s0 + 1];
            float4 p10 = mc[2 * (size_t)s1], p11 = mc[2 * (size_t)s1 + 1];
            float4 p20 = mc[2 * (size_t)s2], p21 = mc[2 * (size_t)s2 + 1];
            float4 p30 = mc[2 * (size_t)s3], p31 = mc[2 * (size_t)s3 + 1];
            a0.x += w0*p00.x + w1*p10.x + w2*p20.x + w3*p30.x;
            a0.y += w0*p00.y + w1*p10.y + w2*p20.y + w3*p30.y;
            a0.z += w0*p00.z + w1*p10.z + w2*p20.z + w3*p30.z;
            a0.w += w0*p00.w + w1*p10.w + w2*p20.w + w3*p30.w;
            a1.x += w0*p01.x + w1*p11.x + w2*p21.x + w3*p31.x;
            a1.y += w0*p01.y + w1*p11.y + w2*p21.y + w3*p31.y;
            a1.z += w0*p01.z + w1*p11.z + w2*p21.z + w3*p31.z;
            a1.w += w0*p01.w + w1*p11.w + w2*p21.w + w3*p31.w;
        }
        for (; j < end; ++j) {
            int s = csr[j];
            float w = dinv[s];
            float4 p0 = mc[2 * (size_t)s], p1 = mc[2 * (size_t)s + 1];
            a0.x += w*p0.x; a0.y += w*p0.y; a0.z += w*p0.z; a0.w += w*p0.w;
            a1.x += w*p1.x; a1.y += w*p1.y; a1.z += w*p1.z; a1.w += w*p1.w;
        }
        float4 m0 = mc[2 * (size_t)v], m1 = mc[2 * (size_t)v + 1];
        float4 bv0 = ((const float4*)b2)[chunk * 2];
        float4 bv1 = ((const float4*)b2)[chunk * 2 + 1];
        float iv = dv * dv;
        a0.x = fmaxf(a0.x * dv + iv * m0.x + bv0.x, 0.f);
        a0.y = fmaxf(a0.y * dv + iv * m0.y + bv0.y, 0.f);
        a0.z = fmaxf(a0.z * dv + iv * m0.z + bv0.z, 0.f);
        a0.w = fmaxf(a0.w * dv + iv * m0.w + bv0.w, 0.f);
        a1.x = fmaxf(a1.x * dv + iv * m1.x + bv1.x, 0.f);
        a1.y = fmaxf(a1.y * dv + iv * m1.y + bv1.y, 0.f);
        a1.z = fmaxf(a1.z * dv + iv * m1.z + bv1.z, 0.f);
        a1.w = fmaxf(a1.w * dv + iv * m1.w + bv1.w, 0.f);
        b = batch[v];
    } else {
        a0 = make_float4(0.f, 0.f, 0.f, 0.f);
        a1 = make_float4(0.f, 0.f, 0.f, 0.f);
    }
    int b0 = __shfl(b, 0);
    bool uni = __all(valid && b == b0);
    if (uni) {
#pragma unroll
        for (int mask = 1; mask <= 32; mask <<= 1) {
            a0.x += __shfl_xor(a0.x, mask); a0.y += __shfl_xor(a0.y, mask);
            a0.z += __shfl_xor(a0.z, mask); a0.w += __shfl_xor(a0.w, mask);
            a1.x += __shfl_xor(a1.x, mask); a1.y += __shfl_xor(a1.y, mask);
            a1.z += __shfl_xor(a1.z, mask); a1.w += __shfl_xor(a1.w, mask);
        }
        if ((threadIdx.x & 63) == 0) {
            float* p = pooled + (size_t)b0 * 32 + chunk * 8;
            atomicAdd(p + 0, a0.x); atomicAdd(p + 1, a0.y);
            atomicAdd(p + 2, a0.z); atomicAdd(p + 3, a0.w);
            atomicAdd(p + 4, a1.x); atomicAdd(p + 5, a1.y);
            atomicAdd(p + 6, a1.z); atomicAdd(p + 7, a1.w);
        }
    } else {
        int bq = __shfl(b, threadIdx.x & 48);
        unsigned long long ball = __ballot(valid && b == bq);
        bool qu = ((ball >> (threadIdx.x & 48)) & 0xFFFFull) == 0xFFFFull;
        if (qu) {
#pragma unroll
            for (int mask = 1; mask <= 8; mask <<= 1) {
                a0.x += __shfl_xor(a0.x, mask); a0.y += __shfl_xor(a0.y, mask);
                a0.z += __shfl_xor(a0.z, mask); a0.w += __shfl_xor(a0.w, mask);
                a1.x += __shfl_xor(a1.x, mask); a1.y += __shfl_xor(a1.y, mask);
                a1.z += __shfl_xor(a1.z, mask); a1.w += __shfl_xor(a1.w, mask);
            }
            if ((threadIdx.x & 15) == 0) {
                float* p = pooled + (size_t)bq * 32 + chunk * 8;
                atomicAdd(p + 0, a0.x); atomicAdd(p + 1, a0.y);
                atomicAdd(p + 2, a0.z); atomicAdd(p + 3, a0.w);
                atomicAdd(p + 4, a1.x); atomicAdd(p + 5, a1.y);
                atomicAdd(p + 6, a1.z); atomicAdd(p + 7, a1.w);
            }
        } else if (valid) {
            float* p = pooled + (size_t)b * 32 + chunk * 8;
            atomicAdd(p + 0, a0.x); atomicAdd(p + 1, a0.y);
            atomicAdd(p + 2, a0.z); atomicAdd(p + 3, a0.w);
            atomicAdd(p + 4, a1.x); atomicAdd(p + 5, a1.y);
            atomicAdd(p + 6, a1.z); atomicAdd(p + 7, a1.w);
        }
    }
}

// ---- out[g] = sigmoid(pooled[g,:] @ Wfc + bfc) ------------------------------
__global__ void k_fc(const float* __restrict__ pooled, const float* __restrict__ Wfc,
                     const float* __restrict__ bfc, float* __restrict__ out) {
    int g = blockIdx.x * blockDim.x + threadIdx.x;
    if (g < N_GRAPHS) {
        float s = bfc[0];
#pragma unroll
        for (int o = 0; o < 32; ++o) s += pooled[g * 32 + o] * Wfc[o];
        out[g] = 1.0f / (1.0f + expf(-s));
    }
}

extern "C" void kernel_launch(void* const* d_in, const int* in_sizes, int n_in,
                              void* d_out, int out_size, void* d_ws, size_t ws_size,
                              hipStream_t stream) {
    const int n  = in_sizes[0] / 10;   // 100000 nodes
    const int ne = in_sizes[1] / 2;    // 1600000 edges
    const int nb = (n + 255) >> 8;     // 391 buckets
    const int nbn = (n + 255) >> 8;    // 256-node blocks

    const float* x     = (const float*)d_in[0];
    const int*   ei    = (const int*)d_in[1];
    const int*   batch = (const int*)d_in[2];
    const float* W1    = (const float*)d_in[3];
    const float* b1    = (const float*)d_in[4];
    const float* W2    = (const float*)d_in[5];
    const float* b2    = (const float*)d_in[6];
    const float* Wfc   = (const float*)d_in[7];
    const float* bfc   = (const float*)d_in[8];
    const int* srcp = ei;
    const int* dstp = ei + ne;

    // workspace layout
    char* base = (char*)d_ws;
    size_t off = 0;
    auto take = [&](size_t bytes) { void* p = base + off; off = align_up(off + bytes, 16); return p; };
    int*      cursor    = (int*)     take((size_t)nb * 4);
    int*      bucketBuf = (int*)     take((size_t)nb * CAP * 4);
    int*      csr       = (int*)     take((size_t)nb * CAP * 4);
    unsigned* pk        = (unsigned*)take((size_t)n * 4);
    float*    dinv      = (float*)   take((size_t)n * 4);
    float4*   xpA       = (float4*)  take((size_t)n * 8 * 4);
    float2*   xpB       = (float2*)  take((size_t)n * 2 * 4);
    float4*   zA        = (float4*)  take((size_t)n * 8 * 4);
    float2*   zB        = (float2*)  take((size_t)n * 2 * 4);
    float*    mT        = (float*)   take((size_t)n * 32 * 4);
    float*    pooled    = (float*)   take((size_t)N_GRAPHS * 32 * 4);

    hipMemsetAsync(pooled, 0, (size_t)N_GRAPHS * 32 * sizeof(float), stream);

    k_initCursor<<<(nb + 255) / 256, 256, 0, stream>>>(cursor, nb);
    k_pad2      <<<(n + 255) / 256, 256, 0, stream>>>(x, xpA, xpB, n);
    k_bucketA   <<<(ne + TILE_A - 1) / TILE_A, 256, 0, stream>>>(srcp, dstp, cursor, bucketBuf, ne, nb);
    k_bucketB   <<<nb, 256, 0, stream>>>(cursor, bucketBuf, csr, pk, dinv, n);
    k_gather1c  <<<nbn * 2, 256, 0, stream>>>(csr, pk, dinv, xpA, xpB, zA, zB, n);
    k_lin       <<<(n + 63) / 64, 256, 0, stream>>>(zA, zB, W1, b1, W2, mT, n);
    k_gather2c  <<<nbn * 4, 256, 0, stream>>>(csr, pk, dinv, mT, b2, batch, pooled, n);
    k_fc        <<<2, 256, 0, stream>>>(pooled, Wfc, bfc, (float*)d_out);
}

// Round 8
// 217.841 us; speedup vs baseline: 1.1961x; 1.1961x over previous
//
#include <hip/hip_runtime.h>
#include <hip/hip_fp16.h>
#include <math.h>

#define N_GRAPHS 512
#define CAP 5120          // bucket capacity: mean 4096, sigma 64
#define TILE_A 4096       // edges per phase-A workgroup (16/thread)

static inline size_t align_up(size_t v, size_t a) { return (v + a - 1) / a * a; }

// ---- init per-bucket write cursors to region starts -------------------------
__global__ void k_initCursor(int* __restrict__ cursor, int nb) {
    int i = blockIdx.x * blockDim.x + threadIdx.x;
    if (i < nb) cursor[i] = i * CAP;
}

// ---- split x (n x 10) -> xpA (n x 8 f32) + xpB (n x 2 f32) ------------------
__global__ void k_pad2(const float* __restrict__ x, float4* __restrict__ xpA,
                       float2* __restrict__ xpB, int n) {
    int v = blockIdx.x * 256 + threadIdx.x;
    if (v >= n) return;
    const float* row = x + (size_t)v * 10;
    xpA[2 * (size_t)v]     = make_float4(row[0], row[1], row[2], row[3]);
    xpA[2 * (size_t)v + 1] = make_float4(row[4], row[5], row[6], row[7]);
    xpB[v] = make_float2(row[8], row[9]);
}

// ---- Phase A: partition edges into dst-range buckets ------------------------
__global__ void k_bucketA(const int* __restrict__ src, const int* __restrict__ dst,
                          int* __restrict__ cursor, int* __restrict__ bucketBuf,
                          int ne, int nb) {
    __shared__ int hist[512];
    __shared__ int base[512];
    for (int i = threadIdx.x; i < nb; i += 256) hist[i] = 0;
    __syncthreads();
    int t0 = blockIdx.x * TILE_A + threadIdx.x;
    int s[16], d[16];
#pragma unroll
    for (int k = 0; k < 16; ++k) {
        int e = t0 + k * 256;
        if (e < ne) {
            s[k] = __builtin_nontemporal_load(src + e);
            d[k] = __builtin_nontemporal_load(dst + e);
        } else { s[k] = 0; d[k] = -1; }
    }
#pragma unroll
    for (int k = 0; k < 16; ++k)
        if (d[k] >= 0) atomicAdd(&hist[d[k] >> 8], 1);
    __syncthreads();
    for (int i = threadIdx.x; i < nb; i += 256)
        base[i] = (hist[i] > 0) ? atomicAdd(&cursor[i], hist[i]) : 0;
    __syncthreads();
#pragma unroll
    for (int k = 0; k < 16; ++k)
        if (d[k] >= 0) {
            int b = d[k] >> 8;
            int slot = atomicAdd(&base[b], 1);
            int lim = b * CAP + (CAP - 1);
            if (slot > lim) slot = lim;   // overflow guard (never expected)
            bucketBuf[slot] = (s[k] << 8) | (d[k] & 255);
        }
}

// ---- Phase B: per-bucket counting sort -> csr + packed(beg,deg) + dinv ------
__global__ void k_bucketB(const int* __restrict__ cursor, const int* __restrict__ bucketBuf,
                          int* __restrict__ csr, unsigned* __restrict__ pk,
                          float* __restrict__ dinv, int n) {
    int b = blockIdx.x;
    int beg = b * CAP;
    int cnt = cursor[b] - beg;
    if (cnt > CAP) cnt = CAP;
    __shared__ int hist[256];
    __shared__ int scan[256];
    hist[threadIdx.x] = 0;
    __syncthreads();
    for (int j = threadIdx.x; j < cnt; j += 256)
        atomicAdd(&hist[__builtin_nontemporal_load(bucketBuf + beg + j) & 255], 1);
    __syncthreads();
    int v = hist[threadIdx.x];
    scan[threadIdx.x] = v;
    __syncthreads();
    for (int off = 1; off < 256; off <<= 1) {
        int t = (threadIdx.x >= off) ? scan[threadIdx.x - off] : 0;
        __syncthreads();
        scan[threadIdx.x] += t;
        __syncthreads();
    }
    int excl = scan[threadIdx.x] - v;
    int node = (b << 8) + threadIdx.x;
    if (node < n) {
        pk[node] = (unsigned)(beg + excl) | ((unsigned)v << 22);
        float dd = (float)v + 1.0f;
        dinv[node] = 1.0f / sqrtf(dd);
    }
    __syncthreads();
    hist[threadIdx.x] = excl;   // reuse as scatter cursor
    __syncthreads();
    for (int j = threadIdx.x; j < cnt; j += 256) {
        int pkk = __builtin_nontemporal_load(bucketBuf + beg + j);
        int slot = atomicAdd(&hist[pkk & 255], 1);
        csr[beg + slot] = pkk >> 8;
    }
}

// ---- gather1 pass A (feats 0-7): 2 lanes x float4 per node ------------------
__global__ void k_g1a(const int* __restrict__ csr, const unsigned* __restrict__ pk,
                      const float* __restrict__ dinv, const float4* __restrict__ xpA,
                      float4* __restrict__ zA, int n) {
    int g = threadIdx.x >> 1, half = threadIdx.x & 1;
    int v = blockIdx.x * 128 + g;
    if (v >= n) return;
    unsigned p = pk[v];
    int beg = (int)(p & 0x3FFFFFu), end = beg + (int)(p >> 22);
    float dv = dinv[v], iv = dv * dv;
    float4 acc = make_float4(0.f, 0.f, 0.f, 0.f);
    int j = beg;
    for (; j + 4 <= end; j += 4) {
        int s0 = __builtin_nontemporal_load(csr + j);
        int s1 = __builtin_nontemporal_load(csr + j + 1);
        int s2 = __builtin_nontemporal_load(csr + j + 2);
        int s3 = __builtin_nontemporal_load(csr + j + 3);
        float w0 = dinv[s0], w1 = dinv[s1], w2 = dinv[s2], w3 = dinv[s3];
        float4 r0 = xpA[2 * (size_t)s0 + half];
        float4 r1 = xpA[2 * (size_t)s1 + half];
        float4 r2 = xpA[2 * (size_t)s2 + half];
        float4 r3 = xpA[2 * (size_t)s3 + half];
        acc.x += w0*r0.x + w1*r1.x + w2*r2.x + w3*r3.x;
        acc.y += w0*r0.y + w1*r1.y + w2*r2.y + w3*r3.y;
        acc.z += w0*r0.z + w1*r1.z + w2*r2.z + w3*r3.z;
        acc.w += w0*r0.w + w1*r1.w + w2*r2.w + w3*r3.w;
    }
    for (; j < end; ++j) {
        int s = __builtin_nontemporal_load(csr + j);
        float w = dinv[s];
        float4 r = xpA[2 * (size_t)s + half];
        acc.x += w*r.x; acc.y += w*r.y; acc.z += w*r.z; acc.w += w*r.w;
    }
    float4 xv = xpA[2 * (size_t)v + half];
    acc.x = acc.x * dv + iv * xv.x;
    acc.y = acc.y * dv + iv * xv.y;
    acc.z = acc.z * dv + iv * xv.z;
    acc.w = acc.w * dv + iv * xv.w;
    zA[2 * (size_t)v + half] = acc;
}

// ---- gather1 pass B (feats 8-9): 1 lane x float2 per node -------------------
__global__ void k_g1b(const int* __restrict__ csr, const unsigned* __restrict__ pk,
                      const float* __restrict__ dinv, const float2* __restrict__ xpB,
                      float2* __restrict__ zB, int n) {
    int v = blockIdx.x * 256 + threadIdx.x;
    if (v >= n) return;
    unsigned p = pk[v];
    int beg = (int)(p & 0x3FFFFFu), end = beg + (int)(p >> 22);
    float dv = dinv[v], iv = dv * dv;
    float2 acc = make_float2(0.f, 0.f);
    int j = beg;
    for (; j + 4 <= end; j += 4) {
        int s0 = __builtin_nontemporal_load(csr + j);
        int s1 = __builtin_nontemporal_load(csr + j + 1);
        int s2 = __builtin_nontemporal_load(csr + j + 2);
        int s3 = __builtin_nontemporal_load(csr + j + 3);
        float w0 = dinv[s0], w1 = dinv[s1], w2 = dinv[s2], w3 = dinv[s3];
        float2 r0 = xpB[s0], r1 = xpB[s1], r2 = xpB[s2], r3 = xpB[s3];
        acc.x += w0*r0.x + w1*r1.x + w2*r2.x + w3*r3.x;
        acc.y += w0*r0.y + w1*r1.y + w2*r2.y + w3*r3.y;
    }
    for (; j < end; ++j) {
        int s = __builtin_nontemporal_load(csr + j);
        float w = dinv[s];
        float2 r = xpB[s];
        acc.x += w * r.x; acc.y += w * r.y;
    }
    float2 xv = xpB[v];
    acc.x = acc.x * dv + iv * xv.x;
    acc.y = acc.y * dv + iv * xv.y;
    zB[v] = acc;
}

// ---- lin: m = relu(z@W1+b1)@W2 -> fp16 chunk-major mh[2][n][16] -------------
__global__ void k_lin(const float4* __restrict__ zA, const float2* __restrict__ zB,
                      const float* __restrict__ W1, const float* __restrict__ b1,
                      const float* __restrict__ W2, __half* __restrict__ mh, int n) {
    __shared__ float W1s[640];
    __shared__ float W2s[2048];
    __shared__ float zt[64 * 12];
    __shared__ float hs[64 * 65];
    for (int i = threadIdx.x; i < 640; i += 256)  W1s[i] = W1[i];
    for (int i = threadIdx.x; i < 2048; i += 256) W2s[i] = W2[i];
    {
        int node = threadIdx.x >> 2, q = threadIdx.x & 3;
        int v = blockIdx.x * 64 + node;
        if (v < n) {
            if (q < 2) {
                float4 r = zA[2 * (size_t)v + q];
                zt[node * 12 + q * 4 + 0] = r.x;
                zt[node * 12 + q * 4 + 1] = r.y;
                zt[node * 12 + q * 4 + 2] = r.z;
                zt[node * 12 + q * 4 + 3] = r.w;
            } else if (q == 2) {
                float2 r = zB[v];
                zt[node * 12 + 8] = r.x;
                zt[node * 12 + 9] = r.y;
            }
        } else if (q == 0) {
#pragma unroll
            for (int k = 0; k < 10; ++k) zt[node * 12 + k] = 0.f;
        }
    }
    __syncthreads();
    {
        int node = threadIdx.x & 63, w = threadIdx.x >> 6;
        float zreg[10];
#pragma unroll
        for (int k = 0; k < 10; ++k) zreg[k] = zt[node * 12 + k];
#pragma unroll
        for (int fq = 0; fq < 16; ++fq) {
            int f = w * 16 + fq;
            float s = b1[f];
#pragma unroll
            for (int k = 0; k < 10; ++k) s += zreg[k] * W1s[k * 64 + f];
            hs[node * 65 + f] = fmaxf(s, 0.f);
        }
    }
    __syncthreads();
    {
        int o = threadIdx.x & 31, nb8 = threadIdx.x >> 5;
        int c = o >> 4, within = o & 15;
#pragma unroll
        for (int it = 0; it < 8; ++it) {
            int node = it * 8 + nb8;
            int vv = blockIdx.x * 64 + node;
            if (vv < n) {
                float s = 0.f;
#pragma unroll
                for (int f = 0; f < 64; ++f) s += hs[node * 65 + f] * W2s[f * 32 + o];
                mh[((size_t)c * n + vv) * 16 + within] = __float2half(s);
            }
        }
    }
}

// ---- gather2 one chunk (16 feats fp16) + relu + hierarchical pooled ---------
#define CVT8FMA(qq, ww) do { \
    const __half2* hp_ = (const __half2*)&(qq); \
    float2 f0_ = __half22float2(hp_[0]); \
    float2 f1_ = __half22float2(hp_[1]); \
    float2 f2_ = __half22float2(hp_[2]); \
    float2 f3_ = __half22float2(hp_[3]); \
    a0 += (ww)*f0_.x; a1 += (ww)*f0_.y; a2 += (ww)*f1_.x; a3 += (ww)*f1_.y; \
    a4 += (ww)*f2_.x; a5 += (ww)*f2_.y; a6 += (ww)*f3_.x; a7 += (ww)*f3_.y; } while (0)

__global__ void k_g2(const int* __restrict__ csr, const unsigned* __restrict__ pk,
                     const float* __restrict__ dinv, const __half* __restrict__ mhc,
                     const float* __restrict__ b2c, const int* __restrict__ batch,
                     float* __restrict__ pooledc, int n) {
    int g = threadIdx.x >> 1, half = threadIdx.x & 1;
    int v = blockIdx.x * 128 + g;
    bool valid = (v < n);
    float a0=0.f,a1=0.f,a2=0.f,a3=0.f,a4=0.f,a5=0.f,a6=0.f,a7=0.f;
    float h[8] = {0.f,0.f,0.f,0.f,0.f,0.f,0.f,0.f};
    int b = -1;
    if (valid) {
        unsigned p = pk[v];
        int beg = (int)(p & 0x3FFFFFu), end = beg + (int)(p >> 22);
        float dv = dinv[v], iv = dv * dv;
        int j = beg;
        for (; j + 4 <= end; j += 4) {
            int s0 = __builtin_nontemporal_load(csr + j);
            int s1 = __builtin_nontemporal_load(csr + j + 1);
            int s2 = __builtin_nontemporal_load(csr + j + 2);
            int s3 = __builtin_nontemporal_load(csr + j + 3);
            float w0 = dinv[s0], w1 = dinv[s1], w2 = dinv[s2], w3 = dinv[s3];
            float4 q0 = *(const float4*)(mhc + (size_t)s0 * 16 + half * 8);
            float4 q1 = *(const float4*)(mhc + (size_t)s1 * 16 + half * 8);
            float4 q2 = *(const float4*)(mhc + (size_t)s2 * 16 + half * 8);
            float4 q3 = *(const float4*)(mhc + (size_t)s3 * 16 + half * 8);
            CVT8FMA(q0, w0); CVT8FMA(q1, w1); CVT8FMA(q2, w2); CVT8FMA(q3, w3);
        }
        for (; j < end; ++j) {
            int s = __builtin_nontemporal_load(csr + j);
            float w = dinv[s];
            float4 q = *(const float4*)(mhc + (size_t)s * 16 + half * 8);
            CVT8FMA(q, w);
        }
        float4 qs = *(const float4*)(mhc + (size_t)v * 16 + half * 8);
        const __half2* sp = (const __half2*)&qs;
        float2 m0 = __half22float2(sp[0]), m1 = __half22float2(sp[1]);
        float2 m2 = __half22float2(sp[2]), m3 = __half22float2(sp[3]);
        const float* bb = b2c + half * 8;
        h[0] = fmaxf(a0 * dv + iv * m0.x + bb[0], 0.f);
        h[1] = fmaxf(a1 * dv + iv * m0.y + bb[1], 0.f);
        h[2] = fmaxf(a2 * dv + iv * m1.x + bb[2], 0.f);
        h[3] = fmaxf(a3 * dv + iv * m1.y + bb[3], 0.f);
        h[4] = fmaxf(a4 * dv + iv * m2.x + bb[4], 0.f);
        h[5] = fmaxf(a5 * dv + iv * m2.y + bb[5], 0.f);
        h[6] = fmaxf(a6 * dv + iv * m3.x + bb[6], 0.f);
        h[7] = fmaxf(a7 * dv + iv * m3.y + bb[7], 0.f);
        b = batch[v];
    }
    int b0 = __shfl(b, 0);
    bool uni = __all(valid && b == b0);
    if (uni) {
#pragma unroll
        for (int mask = 2; mask <= 32; mask <<= 1)
#pragma unroll
            for (int i = 0; i < 8; ++i) h[i] += __shfl_xor(h[i], mask);
        if ((threadIdx.x & 63) < 2) {
            float* pp = pooledc + (size_t)b0 * 32 + half * 8;
#pragma unroll
            for (int i = 0; i < 8; ++i) atomicAdd(pp + i, h[i]);
        }
    } else {
        int bq = __shfl(b, threadIdx.x & 48);
        unsigned long long ball = __ballot(valid && b == bq);
        bool qu = ((ball >> (threadIdx.x & 48)) & 0xFFFFull) == 0xFFFFull;
        if (qu) {
#pragma unroll
            for (int mask = 2; mask <= 8; mask <<= 1)
#pragma unroll
                for (int i = 0; i < 8; ++i) h[i] += __shfl_xor(h[i], mask);
            if ((threadIdx.x & 15) < 2) {
                float* pp = pooledc + (size_t)bq * 32 + half * 8;
#pragma unroll
                for (int i = 0; i < 8; ++i) atomicAdd(pp + i, h[i]);
            }
        } else if (valid) {
            float* pp = pooledc + (size_t)b * 32 + half * 8;
#pragma unroll
            for (int i = 0; i < 8; ++i) atomicAdd(pp + i, h[i]);
        }
    }
}

// ---- out[g] = sigmoid(pooled[g,:] @ Wfc + bfc) ------------------------------
__global__ void k_fc(const float* __restrict__ pooled, const float* __restrict__ Wfc,
                     const float* __restrict__ bfc, float* __restrict__ out) {
    int g = blockIdx.x * blockDim.x + threadIdx.x;
    if (g < N_GRAPHS) {
        float s = bfc[0];
#pragma unroll
        for (int o = 0; o < 32; ++o) s += pooled[g * 32 + o] * Wfc[o];
        out[g] = 1.0f / (1.0f + expf(-s));
    }
}

extern "C" void kernel_launch(void* const* d_in, const int* in_sizes, int n_in,
                              void* d_out, int out_size, void* d_ws, size_t ws_size,
                              hipStream_t stream) {
    const int n  = in_sizes[0] / 10;   // 100000 nodes
    const int ne = in_sizes[1] / 2;    // 1600000 edges
    const int nb = (n + 255) >> 8;     // 391 buckets

    const float* x     = (const float*)d_in[0];
    const int*   ei    = (const int*)d_in[1];
    const int*   batch = (const int*)d_in[2];
    const float* W1    = (const float*)d_in[3];
    const float* b1    = (const float*)d_in[4];
    const float* W2    = (const float*)d_in[5];
    const float* b2    = (const float*)d_in[6];
    const float* Wfc   = (const float*)d_in[7];
    const float* bfc   = (const float*)d_in[8];
    const int* srcp = ei;
    const int* dstp = ei + ne;

    // workspace layout
    char* base = (char*)d_ws;
    size_t off = 0;
    auto take = [&](size_t bytes) { void* p = base + off; off = align_up(off + bytes, 16); return p; };
    int*      cursor    = (int*)     take((size_t)nb * 4);
    int*      bucketBuf = (int*)     take((size_t)nb * CAP * 4);
    int*      csr       = (int*)     take((size_t)nb * CAP * 4);
    unsigned* pk        = (unsigned*)take((size_t)n * 4);
    float*    dinv      = (float*)   take((size_t)n * 4);
    float4*   xpA       = (float4*)  take((size_t)n * 8 * 4);
    float2*   xpB       = (float2*)  take((size_t)n * 2 * 4);
    float4*   zA        = (float4*)  take((size_t)n * 8 * 4);
    float2*   zB        = (float2*)  take((size_t)n * 2 * 4);
    __half*   mh        = (__half*)  take((size_t)n * 32 * 2);   // [2][n][16]
    float*    pooled    = (float*)   take((size_t)N_GRAPHS * 32 * 4);

    hipMemsetAsync(pooled, 0, (size_t)N_GRAPHS * 32 * sizeof(float), stream);

    k_initCursor<<<(nb + 255) / 256, 256, 0, stream>>>(cursor, nb);
    k_pad2      <<<(n + 255) / 256, 256, 0, stream>>>(x, xpA, xpB, n);
    k_bucketA   <<<(ne + TILE_A - 1) / TILE_A, 256, 0, stream>>>(srcp, dstp, cursor, bucketBuf, ne, nb);
    k_bucketB   <<<nb, 256, 0, stream>>>(cursor, bucketBuf, csr, pk, dinv, n);
    // layer-1 aggregation: two sequential passes, each with an L2-resident table
    k_g1a       <<<(n + 127) / 128, 256, 0, stream>>>(csr, pk, dinv, xpA, zA, n);
    k_g1b       <<<(n + 255) / 256, 256, 0, stream>>>(csr, pk, dinv, xpB, zB, n);
    k_lin       <<<(n + 63) / 64,   256, 0, stream>>>(zA, zB, W1, b1, W2, mh, n);
    // layer-2 aggregation: two sequential fp16 chunk passes (3.2 MB tables)
    k_g2        <<<(n + 127) / 128, 256, 0, stream>>>(csr, pk, dinv, mh,
                                                      b2, batch, pooled, n);
    k_g2        <<<(n + 127) / 128, 256, 0, stream>>>(csr, pk, dinv, mh + (size_t)n * 16,
                                                      b2 + 16, batch, pooled + 16, n);
    k_fc        <<<2, 256, 0, stream>>>(pooled, Wfc, bfc, (float*)d_out);
}

// Round 9
// 192.113 us; speedup vs baseline: 1.3563x; 1.1339x over previous
//
#include <hip/hip_runtime.h>
#include <hip/hip_fp16.h>
#include <math.h>

#define N_GRAPHS 512
#define CAP 5120          // bucket capacity: mean 4096, sigma 64
#define TILE_A 4096       // edges per phase-A workgroup (16/thread)

static inline size_t align_up(size_t v, size_t a) { return (v + a - 1) / a * a; }

// ---- init: bucket cursors + zero pooled -------------------------------------
__global__ void k_init(int* __restrict__ cursor, float* __restrict__ pooled, int nb) {
    int i = blockIdx.x * blockDim.x + threadIdx.x;
    if (i < nb) cursor[i] = i * CAP;
    if (i < N_GRAPHS * 32) pooled[i] = 0.f;
}

// ---- x (n x 10 f32) -> xh (n x 16 fp16, zero-padded) ------------------------
__global__ void k_padh(const float* __restrict__ x, __half* __restrict__ xh, int n) {
    int v = blockIdx.x * 256 + threadIdx.x;
    if (v >= n) return;
    const float* row = x + (size_t)v * 10;
    float vals[16];
#pragma unroll
    for (int k = 0; k < 10; ++k) vals[k] = row[k];
#pragma unroll
    for (int k = 10; k < 16; ++k) vals[k] = 0.f;
    __half2 out[8];
#pragma unroll
    for (int i = 0; i < 8; ++i) out[i] = __floats2half2_rn(vals[2 * i], vals[2 * i + 1]);
    *(float4*)(xh + (size_t)v * 16)     = *(float4*)(out);
    *(float4*)(xh + (size_t)v * 16 + 8) = *(float4*)(out + 4);
}

// ---- Phase A: partition edges into dst-range buckets ------------------------
__global__ void k_bucketA(const int* __restrict__ src, const int* __restrict__ dst,
                          int* __restrict__ cursor, int* __restrict__ bucketBuf,
                          int ne, int nb) {
    __shared__ int hist[512];
    __shared__ int base[512];
    for (int i = threadIdx.x; i < nb; i += 256) hist[i] = 0;
    __syncthreads();
    int t0 = blockIdx.x * TILE_A + threadIdx.x;
    int s[16], d[16];
#pragma unroll
    for (int k = 0; k < 16; ++k) {
        int e = t0 + k * 256;
        if (e < ne) {
            s[k] = __builtin_nontemporal_load(src + e);
            d[k] = __builtin_nontemporal_load(dst + e);
        } else { s[k] = 0; d[k] = -1; }
    }
#pragma unroll
    for (int k = 0; k < 16; ++k)
        if (d[k] >= 0) atomicAdd(&hist[d[k] >> 8], 1);
    __syncthreads();
    for (int i = threadIdx.x; i < nb; i += 256)
        base[i] = (hist[i] > 0) ? atomicAdd(&cursor[i], hist[i]) : 0;
    __syncthreads();
#pragma unroll
    for (int k = 0; k < 16; ++k)
        if (d[k] >= 0) {
            int b = d[k] >> 8;
            int slot = atomicAdd(&base[b], 1);
            int lim = b * CAP + (CAP - 1);
            if (slot > lim) slot = lim;   // overflow guard (never expected)
            bucketBuf[slot] = (s[k] << 8) | (d[k] & 255);
        }
}

// ---- Phase B: per-bucket counting sort -> csr + packed(beg,deg) + dinv ------
__global__ void k_bucketB(const int* __restrict__ cursor, const int* __restrict__ bucketBuf,
                          int* __restrict__ csr, unsigned* __restrict__ pk,
                          float* __restrict__ dinv, int n) {
    int b = blockIdx.x;
    int beg = b * CAP;
    int cnt = cursor[b] - beg;
    if (cnt > CAP) cnt = CAP;
    __shared__ int hist[256];
    __shared__ int scan[256];
    hist[threadIdx.x] = 0;
    __syncthreads();
    for (int j = threadIdx.x; j < cnt; j += 256)
        atomicAdd(&hist[__builtin_nontemporal_load(bucketBuf + beg + j) & 255], 1);
    __syncthreads();
    int v = hist[threadIdx.x];
    scan[threadIdx.x] = v;
    __syncthreads();
    for (int off = 1; off < 256; off <<= 1) {
        int t = (threadIdx.x >= off) ? scan[threadIdx.x - off] : 0;
        __syncthreads();
        scan[threadIdx.x] += t;
        __syncthreads();
    }
    int excl = scan[threadIdx.x] - v;
    int node = (b << 8) + threadIdx.x;
    if (node < n) {
        pk[node] = (unsigned)(beg + excl) | ((unsigned)v << 22);
        float dd = (float)v + 1.0f;
        dinv[node] = 1.0f / sqrtf(dd);
    }
    __syncthreads();
    hist[threadIdx.x] = excl;   // reuse as scatter cursor
    __syncthreads();
    for (int j = threadIdx.x; j < cnt; j += 256) {
        int pkk = __builtin_nontemporal_load(bucketBuf + beg + j);
        int slot = atomicAdd(&hist[pkk & 255], 1);
        csr[beg + slot] = pkk >> 8;
    }
}

// 8 fp16 feats -> fma into a0..a7
#define CVT8FMA(qq, ww) do { \
    const __half2* hp_ = (const __half2*)&(qq); \
    float2 f0_ = __half22float2(hp_[0]); \
    float2 f1_ = __half22float2(hp_[1]); \
    float2 f2_ = __half22float2(hp_[2]); \
    float2 f3_ = __half22float2(hp_[3]); \
    a0 += (ww)*f0_.x; a1 += (ww)*f0_.y; a2 += (ww)*f1_.x; a3 += (ww)*f1_.y; \
    a4 += (ww)*f2_.x; a5 += (ww)*f2_.y; a6 += (ww)*f3_.x; a7 += (ww)*f3_.y; } while (0)

#define RED8(mask) do { \
    a0 += __shfl_xor(a0, mask); a1 += __shfl_xor(a1, mask); \
    a2 += __shfl_xor(a2, mask); a3 += __shfl_xor(a3, mask); \
    a4 += __shfl_xor(a4, mask); a5 += __shfl_xor(a5, mask); \
    a6 += __shfl_xor(a6, mask); a7 += __shfl_xor(a7, mask); } while (0)

// lane layout: node-slot = lane>>3 (8 nodes/wave); half = lane&1; edge-slot q = (lane>>1)&3

// ---- gather1: z[v][0:16] = dv*sum(dinv[s]*xh[s]) + iv*xh[v]  (fp32 out) -----
__global__ void k_gath1(const int* __restrict__ csr, const unsigned* __restrict__ pk,
                        const float* __restrict__ dinv, const __half* __restrict__ xh,
                        float* __restrict__ z, int n) {
    int half = threadIdx.x & 1;
    int q = (threadIdx.x >> 1) & 3;
    int v = blockIdx.x * 32 + (threadIdx.x >> 3);
    if (v >= n) return;
    unsigned p = pk[v];
    int beg = (int)(p & 0x3FFFFFu), end = beg + (int)(p >> 22);
    float dv = dinv[v], iv = dv * dv;
    float a0=0.f,a1=0.f,a2=0.f,a3=0.f,a4=0.f,a5=0.f,a6=0.f,a7=0.f;
    int j = beg + q;
    for (; j + 4 < end; j += 8) {
        int sA = __builtin_nontemporal_load(csr + j);
        int sB = __builtin_nontemporal_load(csr + j + 4);
        float wA = dinv[sA], wB = dinv[sB];
        float4 qA = *(const float4*)(xh + (size_t)sA * 16 + half * 8);
        float4 qB = *(const float4*)(xh + (size_t)sB * 16 + half * 8);
        CVT8FMA(qA, wA); CVT8FMA(qB, wB);
    }
    if (j < end) {
        int s = __builtin_nontemporal_load(csr + j);
        float w = dinv[s];
        float4 qq = *(const float4*)(xh + (size_t)s * 16 + half * 8);
        CVT8FMA(qq, w);
    }
    RED8(2); RED8(4);
    if (q == 0) {
        float4 qs = *(const float4*)(xh + (size_t)v * 16 + half * 8);
        const __half2* sp = (const __half2*)&qs;
        float2 s0 = __half22float2(sp[0]), s1 = __half22float2(sp[1]);
        float2 s2 = __half22float2(sp[2]), s3 = __half22float2(sp[3]);
        float4 o0 = make_float4(a0*dv + iv*s0.x, a1*dv + iv*s0.y, a2*dv + iv*s1.x, a3*dv + iv*s1.y);
        float4 o1 = make_float4(a4*dv + iv*s2.x, a5*dv + iv*s2.y, a6*dv + iv*s3.x, a7*dv + iv*s3.y);
        *(float4*)(z + (size_t)v * 16 + half * 8)     = o0;
        *(float4*)(z + (size_t)v * 16 + half * 8 + 4) = o1;
    }
}

// ---- lin: m = relu(z@W1+b1)@W2 -> fp16 chunk-major mh[2][n][16] -------------
__global__ void k_lin(const float* __restrict__ z, const float* __restrict__ W1,
                      const float* __restrict__ b1, const float* __restrict__ W2,
                      __half* __restrict__ mh, int n) {
    __shared__ float W1s[640];
    __shared__ float W2s[2048];
    __shared__ float zt[64 * 17];
    __shared__ float hs[64 * 65];
    for (int i = threadIdx.x; i < 640; i += 256)  W1s[i] = W1[i];
    for (int i = threadIdx.x; i < 2048; i += 256) W2s[i] = W2[i];
    {
        int node = threadIdx.x >> 2, qq = threadIdx.x & 3;
        int v = blockIdx.x * 64 + node;
        if (qq < 3) {
            float4 r = make_float4(0.f, 0.f, 0.f, 0.f);
            if (v < n) r = *(const float4*)(z + (size_t)v * 16 + qq * 4);
            zt[node * 17 + qq * 4 + 0] = r.x;
            zt[node * 17 + qq * 4 + 1] = r.y;
            zt[node * 17 + qq * 4 + 2] = r.z;
            zt[node * 17 + qq * 4 + 3] = r.w;
        }
    }
    __syncthreads();
    {
        int node = threadIdx.x & 63, w = threadIdx.x >> 6;
        float zreg[10];
#pragma unroll
        for (int k = 0; k < 10; ++k) zreg[k] = zt[node * 17 + k];
#pragma unroll
        for (int fq = 0; fq < 16; ++fq) {
            int f = w * 16 + fq;
            float s = b1[f];
#pragma unroll
            for (int k = 0; k < 10; ++k) s += zreg[k] * W1s[k * 64 + f];
            hs[node * 65 + f] = fmaxf(s, 0.f);
        }
    }
    __syncthreads();
    {
        int o = threadIdx.x & 31, nb8 = threadIdx.x >> 5;
        int c = o >> 4, within = o & 15;
#pragma unroll
        for (int it = 0; it < 8; ++it) {
            int node = it * 8 + nb8;
            int vv = blockIdx.x * 64 + node;
            if (vv < n) {
                float s = 0.f;
#pragma unroll
                for (int f = 0; f < 64; ++f) s += hs[node * 65 + f] * W2s[f * 32 + o];
                mh[((size_t)c * n + vv) * 16 + within] = __float2half(s);
            }
        }
    }
}

// ---- gather2 one chunk (16 fp16 feats) + relu + pooled ----------------------
__global__ void k_gath2(const int* __restrict__ csr, const unsigned* __restrict__ pk,
                        const float* __restrict__ dinv, const __half* __restrict__ mhc,
                        const float* __restrict__ b2c, const int* __restrict__ batch,
                        float* __restrict__ pooledc, int n) {
    int half = threadIdx.x & 1;
    int q = (threadIdx.x >> 1) & 3;
    int v = blockIdx.x * 32 + (threadIdx.x >> 3);
    bool valid = (v < n);
    float a0=0.f,a1=0.f,a2=0.f,a3=0.f,a4=0.f,a5=0.f,a6=0.f,a7=0.f;
    float dv = 0.f, iv = 0.f;
    int b = -1;
    if (valid) {
        unsigned p = pk[v];
        int beg = (int)(p & 0x3FFFFFu), end = beg + (int)(p >> 22);
        dv = dinv[v]; iv = dv * dv;
        int j = beg + q;
        for (; j + 4 < end; j += 8) {
            int sA = __builtin_nontemporal_load(csr + j);
            int sB = __builtin_nontemporal_load(csr + j + 4);
            float wA = dinv[sA], wB = dinv[sB];
            float4 qA = *(const float4*)(mhc + (size_t)sA * 16 + half * 8);
            float4 qB = *(const float4*)(mhc + (size_t)sB * 16 + half * 8);
            CVT8FMA(qA, wA); CVT8FMA(qB, wB);
        }
        if (j < end) {
            int s = __builtin_nontemporal_load(csr + j);
            float w = dinv[s];
            float4 qq = *(const float4*)(mhc + (size_t)s * 16 + half * 8);
            CVT8FMA(qq, w);
        }
        b = batch[v];
    }
    RED8(2); RED8(4);
    float h0=0.f,h1=0.f,h2=0.f,h3=0.f,h4=0.f,h5=0.f,h6=0.f,h7=0.f;
    if (valid && q == 0) {
        float4 qs = *(const float4*)(mhc + (size_t)v * 16 + half * 8);
        const __half2* sp = (const __half2*)&qs;
        float2 s0 = __half22float2(sp[0]), s1 = __half22float2(sp[1]);
        float2 s2 = __half22float2(sp[2]), s3 = __half22float2(sp[3]);
        const float* bb = b2c + half * 8;
        h0 = fmaxf(a0*dv + iv*s0.x + bb[0], 0.f);
        h1 = fmaxf(a1*dv + iv*s0.y + bb[1], 0.f);
        h2 = fmaxf(a2*dv + iv*s1.x + bb[2], 0.f);
        h3 = fmaxf(a3*dv + iv*s1.y + bb[3], 0.f);
        h4 = fmaxf(a4*dv + iv*s2.x + bb[4], 0.f);
        h5 = fmaxf(a5*dv + iv*s2.y + bb[5], 0.f);
        h6 = fmaxf(a6*dv + iv*s3.x + bb[6], 0.f);
        h7 = fmaxf(a7*dv + iv*s3.y + bb[7], 0.f);
    }
    int b0 = __shfl(b, 0);
    bool uni = __all(!valid || b == b0);
    if (uni) {
#pragma unroll
        for (int mask = 8; mask <= 32; mask <<= 1) {
            h0 += __shfl_xor(h0, mask); h1 += __shfl_xor(h1, mask);
            h2 += __shfl_xor(h2, mask); h3 += __shfl_xor(h3, mask);
            h4 += __shfl_xor(h4, mask); h5 += __shfl_xor(h5, mask);
            h6 += __shfl_xor(h6, mask); h7 += __shfl_xor(h7, mask);
        }
        if ((threadIdx.x & 63) < 2 && b0 >= 0) {
            float* pp = pooledc + (size_t)b0 * 32 + half * 8;
            atomicAdd(pp + 0, h0); atomicAdd(pp + 1, h1);
            atomicAdd(pp + 2, h2); atomicAdd(pp + 3, h3);
            atomicAdd(pp + 4, h4); atomicAdd(pp + 5, h5);
            atomicAdd(pp + 6, h6); atomicAdd(pp + 7, h7);
        }
    } else if (valid && q == 0) {
        float* pp = pooledc + (size_t)b * 32 + half * 8;
        atomicAdd(pp + 0, h0); atomicAdd(pp + 1, h1);
        atomicAdd(pp + 2, h2); atomicAdd(pp + 3, h3);
        atomicAdd(pp + 4, h4); atomicAdd(pp + 5, h5);
        atomicAdd(pp + 6, h6); atomicAdd(pp + 7, h7);
    }
}

// ---- out[g] = sigmoid(pooled[g,:] @ Wfc + bfc) ------------------------------
__global__ void k_fc(const float* __restrict__ pooled, const float* __restrict__ Wfc,
                     const float* __restrict__ bfc, float* __restrict__ out) {
    int g = blockIdx.x * blockDim.x + threadIdx.x;
    if (g < N_GRAPHS) {
        float s = bfc[0];
#pragma unroll
        for (int o = 0; o < 32; ++o) s += pooled[g * 32 + o] * Wfc[o];
        out[g] = 1.0f / (1.0f + expf(-s));
    }
}

extern "C" void kernel_launch(void* const* d_in, const int* in_sizes, int n_in,
                              void* d_out, int out_size, void* d_ws, size_t ws_size,
                              hipStream_t stream) {
    const int n  = in_sizes[0] / 10;   // 100000 nodes
    const int ne = in_sizes[1] / 2;    // 1600000 edges
    const int nb = (n + 255) >> 8;     // 391 buckets

    const float* x     = (const float*)d_in[0];
    const int*   ei    = (const int*)d_in[1];
    const int*   batch = (const int*)d_in[2];
    const float* W1    = (const float*)d_in[3];
    const float* b1    = (const float*)d_in[4];
    const float* W2    = (const float*)d_in[5];
    const float* b2    = (const float*)d_in[6];
    const float* Wfc   = (const float*)d_in[7];
    const float* bfc   = (const float*)d_in[8];
    const int* srcp = ei;
    const int* dstp = ei + ne;

    // workspace layout
    char* base = (char*)d_ws;
    size_t off = 0;
    auto take = [&](size_t bytes) { void* p = base + off; off = align_up(off + bytes, 16); return p; };
    int*      cursor    = (int*)     take((size_t)nb * 4);
    int*      bucketBuf = (int*)     take((size_t)nb * CAP * 4);
    int*      csr       = (int*)     take((size_t)nb * CAP * 4);
    unsigned* pk        = (unsigned*)take((size_t)n * 4);
    float*    dinv      = (float*)   take((size_t)n * 4);
    __half*   xh        = (__half*)  take((size_t)n * 16 * 2);
    float*    z         = (float*)   take((size_t)n * 16 * 4);
    __half*   mh        = (__half*)  take((size_t)n * 32 * 2);   // [2][n][16]
    float*    pooled    = (float*)   take((size_t)N_GRAPHS * 32 * 4);

    k_init   <<<64, 256, 0, stream>>>(cursor, pooled, nb);
    k_padh   <<<(n + 255) / 256, 256, 0, stream>>>(x, xh, n);
    k_bucketA<<<(ne + TILE_A - 1) / TILE_A, 256, 0, stream>>>(srcp, dstp, cursor, bucketBuf, ne, nb);
    k_bucketB<<<nb, 256, 0, stream>>>(cursor, bucketBuf, csr, pk, dinv, n);
    k_gath1  <<<(n + 31) / 32, 256, 0, stream>>>(csr, pk, dinv, xh, z, n);
    k_lin    <<<(n + 63) / 64, 256, 0, stream>>>(z, W1, b1, W2, mh, n);
    k_gath2  <<<(n + 31) / 32, 256, 0, stream>>>(csr, pk, dinv, mh,
                                                 b2, batch, pooled, n);
    k_gath2  <<<(n + 31) / 32, 256, 0, stream>>>(csr, pk, dinv, mh + (size_t)n * 16,
                                                 b2 + 16, batch, pooled + 16, n);
    k_fc     <<<2, 256, 0, stream>>>(pooled, Wfc, bfc, (float*)d_out);
}

// Round 11
// 167.196 us; speedup vs baseline: 1.5585x; 1.1490x over previous
//
#include <hip/hip_runtime.h>
#include <hip/hip_fp16.h>
#include <math.h>

#define N_GRAPHS 512
#define CAP 5120          // bucket capacity: mean 4096, sigma 64
#define TILE_A 4096       // edges per phase-A workgroup (16/thread)

static inline size_t align_up(size_t v, size_t a) { return (v + a - 1) / a * a; }

// ---- init: bucket cursors + zero scalar pooled ------------------------------
__global__ void k_init(int* __restrict__ cursor, float* __restrict__ pooledS, int nb) {
    int i = blockIdx.x * blockDim.x + threadIdx.x;
    if (i < nb) cursor[i] = i * CAP;
    if (i < N_GRAPHS) pooledS[i] = 0.f;
}

// ---- Phase A: partition edges into dst-range buckets ------------------------
__global__ void k_bucketA(const int* __restrict__ src, const int* __restrict__ dst,
                          int* __restrict__ cursor, int* __restrict__ bucketBuf,
                          int ne, int nb) {
    __shared__ int hist[512];
    __shared__ int base[512];
    for (int i = threadIdx.x; i < nb; i += 256) hist[i] = 0;
    __syncthreads();
    int t0 = blockIdx.x * TILE_A + threadIdx.x;
    int s[16], d[16];
#pragma unroll
    for (int k = 0; k < 16; ++k) {
        int e = t0 + k * 256;
        if (e < ne) {
            s[k] = __builtin_nontemporal_load(src + e);
            d[k] = __builtin_nontemporal_load(dst + e);
        } else { s[k] = 0; d[k] = -1; }
    }
#pragma unroll
    for (int k = 0; k < 16; ++k)
        if (d[k] >= 0) atomicAdd(&hist[d[k] >> 8], 1);
    __syncthreads();
    for (int i = threadIdx.x; i < nb; i += 256)
        base[i] = (hist[i] > 0) ? atomicAdd(&cursor[i], hist[i]) : 0;
    __syncthreads();
#pragma unroll
    for (int k = 0; k < 16; ++k)
        if (d[k] >= 0) {
            int b = d[k] >> 8;
            int slot = atomicAdd(&base[b], 1);
            int lim = b * CAP + (CAP - 1);
            if (slot > lim) slot = lim;   // overflow guard (never expected)
            bucketBuf[slot] = (s[k] << 8) | (d[k] & 255);
        }
}

// ---- Phase B: per-bucket counting sort -> csr + packed(beg,deg) + dinv ------
__global__ void k_bucketB(const int* __restrict__ cursor, const int* __restrict__ bucketBuf,
                          int* __restrict__ csr, unsigned* __restrict__ pk,
                          float* __restrict__ dinv, int n) {
    int b = blockIdx.x;
    int beg = b * CAP;
    int cnt = cursor[b] - beg;
    if (cnt > CAP) cnt = CAP;
    __shared__ int hist[256];
    __shared__ int scan[256];
    hist[threadIdx.x] = 0;
    __syncthreads();
    for (int j = threadIdx.x; j < cnt; j += 256)
        atomicAdd(&hist[__builtin_nontemporal_load(bucketBuf + beg + j) & 255], 1);
    __syncthreads();
    int v = hist[threadIdx.x];
    scan[threadIdx.x] = v;
    __syncthreads();
    for (int off = 1; off < 256; off <<= 1) {
        int t = (threadIdx.x >= off) ? scan[threadIdx.x - off] : 0;
        __syncthreads();
        scan[threadIdx.x] += t;
        __syncthreads();
    }
    int excl = scan[threadIdx.x] - v;
    int node = (b << 8) + threadIdx.x;
    if (node < n) {
        pk[node] = (unsigned)(beg + excl) | ((unsigned)v << 22);
        float dd = (float)v + 1.0f;
        dinv[node] = 1.0f / sqrtf(dd);
    }
    __syncthreads();
    hist[threadIdx.x] = excl;   // reuse as scatter cursor
    __syncthreads();
    for (int j = threadIdx.x; j < cnt; j += 256) {
        int pkk = __builtin_nontemporal_load(bucketBuf + beg + j);
        int slot = atomicAdd(&hist[pkk & 255], 1);
        csr[beg + slot] = pkk >> 8;
    }
}

// ---- xhs[v] = dinv[v] * x[v]  (n x 16 fp16, zero-padded) --------------------
__global__ void k_padh(const float* __restrict__ x, const float* __restrict__ dinv,
                       __half* __restrict__ xh, int n) {
    int v = blockIdx.x * 256 + threadIdx.x;
    if (v >= n) return;
    const float* row = x + (size_t)v * 10;
    float dv = dinv[v];
    float vals[16];
#pragma unroll
    for (int k = 0; k < 10; ++k) vals[k] = row[k] * dv;
#pragma unroll
    for (int k = 10; k < 16; ++k) vals[k] = 0.f;
    __half2 out[8];
#pragma unroll
    for (int i = 0; i < 8; ++i) out[i] = __floats2half2_rn(vals[2 * i], vals[2 * i + 1]);
    *(float4*)(xh + (size_t)v * 16)     = *(float4*)(out);
    *(float4*)(xh + (size_t)v * 16 + 8) = *(float4*)(out + 4);
}

// 8 fp16 feats -> add into a0..a7 (dinv folded into table; plain add)
#define CVT8ADD(qq) do { \
    const __half2* hp_ = (const __half2*)&(qq); \
    float2 f0_ = __half22float2(hp_[0]); \
    float2 f1_ = __half22float2(hp_[1]); \
    float2 f2_ = __half22float2(hp_[2]); \
    float2 f3_ = __half22float2(hp_[3]); \
    a0 += f0_.x; a1 += f0_.y; a2 += f1_.x; a3 += f1_.y; \
    a4 += f2_.x; a5 += f2_.y; a6 += f3_.x; a7 += f3_.y; } while (0)

#define RED8(mask) do { \
    a0 += __shfl_xor(a0, mask); a1 += __shfl_xor(a1, mask); \
    a2 += __shfl_xor(a2, mask); a3 += __shfl_xor(a3, mask); \
    a4 += __shfl_xor(a4, mask); a5 += __shfl_xor(a5, mask); \
    a6 += __shfl_xor(a6, mask); a7 += __shfl_xor(a7, mask); } while (0)

// lane layout: half = lane&1; edge-slot q = (lane>>1)&3; node-slot = lane>>3

// ---- gather1: z[v] = dv*(sum_edges xhs[s] + xhs[v])  (fp32 out) -------------
__global__ void k_gath1(const int* __restrict__ csr, const unsigned* __restrict__ pk,
                        const float* __restrict__ dinv, const __half* __restrict__ xh,
                        float* __restrict__ z, int n) {
    int half = threadIdx.x & 1;
    int q = (threadIdx.x >> 1) & 3;
    int v = blockIdx.x * 32 + (threadIdx.x >> 3);
    if (v >= n) return;
    unsigned p = pk[v];
    int beg = (int)(p & 0x3FFFFFu), end = beg + (int)(p >> 22);
    float a0=0.f,a1=0.f,a2=0.f,a3=0.f,a4=0.f,a5=0.f,a6=0.f,a7=0.f;
    int j = beg + q;
    for (; j + 4 < end; j += 8) {
        int sA = __builtin_nontemporal_load(csr + j);
        int sB = __builtin_nontemporal_load(csr + j + 4);
        float4 qA = *(const float4*)(xh + (size_t)sA * 16 + half * 8);
        float4 qB = *(const float4*)(xh + (size_t)sB * 16 + half * 8);
        CVT8ADD(qA); CVT8ADD(qB);
    }
    if (j < end) {
        int s = __builtin_nontemporal_load(csr + j);
        float4 qq = *(const float4*)(xh + (size_t)s * 16 + half * 8);
        CVT8ADD(qq);
    }
    RED8(2); RED8(4);
    if (q == 0) {
        float dv = dinv[v];
        float4 qs = *(const float4*)(xh + (size_t)v * 16 + half * 8);
        const __half2* sp = (const __half2*)&qs;
        float2 s0 = __half22float2(sp[0]), s1 = __half22float2(sp[1]);
        float2 s2 = __half22float2(sp[2]), s3 = __half22float2(sp[3]);
        float4 o0 = make_float4((a0 + s0.x) * dv, (a1 + s0.y) * dv,
                                (a2 + s1.x) * dv, (a3 + s1.y) * dv);
        float4 o1 = make_float4((a4 + s2.x) * dv, (a5 + s2.y) * dv,
                                (a6 + s3.x) * dv, (a7 + s3.y) * dv);
        *(float4*)(z + (size_t)v * 16 + half * 8)     = o0;
        *(float4*)(z + (size_t)v * 16 + half * 8 + 4) = o1;
    }
}

// ---- lin: m = relu(z@W1+b1)@W2; store dinv-prescaled fp16 mh[2][n][16] ------
__global__ void k_lin(const float* __restrict__ z, const float* __restrict__ dinv,
                      const float* __restrict__ W1, const float* __restrict__ b1,
                      const float* __restrict__ W2, __half* __restrict__ mh, int n) {
    __shared__ float W1s[640];
    __shared__ float W2s[2048];
    __shared__ float zt[64 * 17];
    __shared__ float hs[64 * 65];
    for (int i = threadIdx.x; i < 640; i += 256)  W1s[i] = W1[i];
    for (int i = threadIdx.x; i < 2048; i += 256) W2s[i] = W2[i];
    {
        int node = threadIdx.x >> 2, qq = threadIdx.x & 3;
        int v = blockIdx.x * 64 + node;
        if (qq < 3) {
            float4 r = make_float4(0.f, 0.f, 0.f, 0.f);
            if (v < n) r = *(const float4*)(z + (size_t)v * 16 + qq * 4);
            zt[node * 17 + qq * 4 + 0] = r.x;
            zt[node * 17 + qq * 4 + 1] = r.y;
            zt[node * 17 + qq * 4 + 2] = r.z;
            zt[node * 17 + qq * 4 + 3] = r.w;
        }
    }
    __syncthreads();
    {
        int node = threadIdx.x & 63, w = threadIdx.x >> 6;
        float zreg[10];
#pragma unroll
        for (int k = 0; k < 10; ++k) zreg[k] = zt[node * 17 + k];
#pragma unroll
        for (int fq = 0; fq < 16; ++fq) {
            int f = w * 16 + fq;
            float s = b1[f];
#pragma unroll
            for (int k = 0; k < 10; ++k) s += zreg[k] * W1s[k * 64 + f];
            hs[node * 65 + f] = fmaxf(s, 0.f);
        }
    }
    __syncthreads();
    {
        int o = threadIdx.x & 31, nb8 = threadIdx.x >> 5;
        int c = o >> 4, within = o & 15;
#pragma unroll
        for (int it = 0; it < 8; ++it) {
            int node = it * 8 + nb8;
            int vv = blockIdx.x * 64 + node;
            if (vv < n) {
                float s = 0.f;
#pragma unroll
                for (int f = 0; f < 64; ++f) s += hs[node * 65 + f] * W2s[f * 32 + o];
                mh[((size_t)c * n + vv) * 16 + within] = __float2half(s * dinv[vv]);
            }
        }
    }
}

// ---- gather2 one chunk + relu + per-node FC dot + scalar pool ---------------
__global__ void k_gath2(const int* __restrict__ csr, const unsigned* __restrict__ pk,
                        const float* __restrict__ dinv, const __half* __restrict__ mhc,
                        const float* __restrict__ b2c, const float* __restrict__ wfcc,
                        const int* __restrict__ batch, float* __restrict__ pooledS, int n) {
    int half = threadIdx.x & 1;
    int q = (threadIdx.x >> 1) & 3;
    int v = blockIdx.x * 32 + (threadIdx.x >> 3);
    bool valid = (v < n);
    float a0=0.f,a1=0.f,a2=0.f,a3=0.f,a4=0.f,a5=0.f,a6=0.f,a7=0.f;
    int b = -1;
    if (valid) {
        unsigned p = pk[v];
        int beg = (int)(p & 0x3FFFFFu), end = beg + (int)(p >> 22);
        int j = beg + q;
        for (; j + 4 < end; j += 8) {
            int sA = __builtin_nontemporal_load(csr + j);
            int sB = __builtin_nontemporal_load(csr + j + 4);
            float4 qA = *(const float4*)(mhc + (size_t)sA * 16 + half * 8);
            float4 qB = *(const float4*)(mhc + (size_t)sB * 16 + half * 8);
            CVT8ADD(qA); CVT8ADD(qB);
        }
        if (j < end) {
            int s = __builtin_nontemporal_load(csr + j);
            float4 qq = *(const float4*)(mhc + (size_t)s * 16 + half * 8);
            CVT8ADD(qq);
        }
        b = batch[v];
    }
    RED8(2); RED8(4);
    float part = 0.f;
    if (valid && q == 0) {
        float dv = dinv[v];
        float4 qs = *(const float4*)(mhc + (size_t)v * 16 + half * 8);
        const __half2* sp = (const __half2*)&qs;
        float2 s0 = __half22float2(sp[0]), s1 = __half22float2(sp[1]);
        float2 s2 = __half22float2(sp[2]), s3 = __half22float2(sp[3]);
        const float* bb = b2c + half * 8;
        const float* wf = wfcc + half * 8;
        part  = fmaxf((a0 + s0.x) * dv + bb[0], 0.f) * wf[0];
        part += fmaxf((a1 + s0.y) * dv + bb[1], 0.f) * wf[1];
        part += fmaxf((a2 + s1.x) * dv + bb[2], 0.f) * wf[2];
        part += fmaxf((a3 + s1.y) * dv + bb[3], 0.f) * wf[3];
        part += fmaxf((a4 + s2.x) * dv + bb[4], 0.f) * wf[4];
        part += fmaxf((a5 + s2.y) * dv + bb[5], 0.f) * wf[5];
        part += fmaxf((a6 + s3.x) * dv + bb[6], 0.f) * wf[6];
        part += fmaxf((a7 + s3.y) * dv + bb[7], 0.f) * wf[7];
    }
    // fold the two half-lanes -> node scalar t[v] on q==0 lanes (both halves hold t)
    part += __shfl_xor(part, 1);
    int b0 = __shfl(b, 0);
    bool uni = __all(!valid || b == b0);
    if (uni) {
        // butterfly over node slots; lane 0's partner set {0,8,...,56} is all
        // half==0/q==0 lanes -> each node's t counted exactly once.
        part += __shfl_xor(part, 8);
        part += __shfl_xor(part, 16);
        part += __shfl_xor(part, 32);
        if ((threadIdx.x & 63) == 0 && b0 >= 0) {
            atomicAdd(pooledS + b0, part);
        }
    } else if (valid && q == 0 && half == 0) {
        atomicAdd(pooledS + b, part);
    }
}

// ---- out[g] = sigmoid(pooledS[g] + bfc) -------------------------------------
__global__ void k_fc(const float* __restrict__ pooledS, const float* __restrict__ bfc,
                     float* __restrict__ out) {
    int g = blockIdx.x * blockDim.x + threadIdx.x;
    if (g < N_GRAPHS) out[g] = 1.0f / (1.0f + expf(-(pooledS[g] + bfc[0])));
}

extern "C" void kernel_launch(void* const* d_in, const int* in_sizes, int n_in,
                              void* d_out, int out_size, void* d_ws, size_t ws_size,
                              hipStream_t stream) {
    const int n  = in_sizes[0] / 10;   // 100000 nodes
    const int ne = in_sizes[1] / 2;    // 1600000 edges
    const int nb = (n + 255) >> 8;     // 391 buckets

    const float* x     = (const float*)d_in[0];
    const int*   ei    = (const int*)d_in[1];
    const int*   batch = (const int*)d_in[2];
    const float* W1    = (const float*)d_in[3];
    const float* b1    = (const float*)d_in[4];
    const float* W2    = (const float*)d_in[5];
    const float* b2    = (const float*)d_in[6];
    const float* Wfc   = (const float*)d_in[7];
    const float* bfc   = (const float*)d_in[8];
    const int* srcp = ei;
    const int* dstp = ei + ne;

    // workspace layout
    char* base = (char*)d_ws;
    size_t off = 0;
    auto take = [&](size_t bytes) { void* p = base + off; off = align_up(off + bytes, 16); return p; };
    int*      cursor    = (int*)     take((size_t)nb * 4);
    int*      bucketBuf = (int*)     take((size_t)nb * CAP * 4);
    int*      csr       = (int*)     take((size_t)nb * CAP * 4);
    unsigned* pk        = (unsigned*)take((size_t)n * 4);
    float*    dinv      = (float*)   take((size_t)n * 4);
    __half*   xh        = (__half*)  take((size_t)n * 16 * 2);
    float*    z         = (float*)   take((size_t)n * 16 * 4);
    __half*   mh        = (__half*)  take((size_t)n * 32 * 2);   // [2][n][16]
    float*    pooledS   = (float*)   take((size_t)N_GRAPHS * 4);

    k_init   <<<4, 256, 0, stream>>>(cursor, pooledS, nb);
    k_bucketA<<<(ne + TILE_A - 1) / TILE_A, 256, 0, stream>>>(srcp, dstp, cursor, bucketBuf, ne, nb);
    k_bucketB<<<nb, 256, 0, stream>>>(cursor, bucketBuf, csr, pk, dinv, n);
    k_padh   <<<(n + 255) / 256, 256, 0, stream>>>(x, dinv, xh, n);
    k_gath1  <<<(n + 31) / 32, 256, 0, stream>>>(csr, pk, dinv, xh, z, n);
    k_lin    <<<(n + 63) / 64, 256, 0, stream>>>(z, dinv, W1, b1, W2, mh, n);
    k_gath2  <<<(n + 31) / 32, 256, 0, stream>>>(csr, pk, dinv, mh,
                                                 b2, Wfc, batch, pooledS, n);
    k_gath2  <<<(n + 31) / 32, 256, 0, stream>>>(csr, pk, dinv, mh + (size_t)n * 16,
                                                 b2 + 16, Wfc + 16, batch, pooledS, n);
    k_fc     <<<2, 256, 0, stream>>>(pooledS, bfc, (float*)d_out);
}

// Round 12
// 156.769 us; speedup vs baseline: 1.6621x; 1.0665x over previous
//
#include <hip/hip_runtime.h>
#include <hip/hip_fp16.h>
#include <math.h>

#define N_GRAPHS 512
#define CAP 5120          // bucket capacity: mean 4096, sigma 64
#define TILE_A 4096       // edges per phase-A workgroup (16/thread)

static inline size_t align_up(size_t v, size_t a) { return (v + a - 1) / a * a; }

// ---- init: bucket cursors + zero scalar pooled ------------------------------
__global__ void k_init(int* __restrict__ cursor, float* __restrict__ pooledS, int nb) {
    int i = blockIdx.x * blockDim.x + threadIdx.x;
    if (i < nb) cursor[i] = i * CAP;
    if (i < N_GRAPHS) pooledS[i] = 0.f;
}

// ---- Phase A: partition edges into dst-range buckets ------------------------
__global__ void k_bucketA(const int* __restrict__ src, const int* __restrict__ dst,
                          int* __restrict__ cursor, int* __restrict__ bucketBuf,
                          int ne, int nb) {
    __shared__ int hist[512];
    __shared__ int base[512];
    for (int i = threadIdx.x; i < nb; i += 256) hist[i] = 0;
    __syncthreads();
    int t0 = blockIdx.x * TILE_A + threadIdx.x;
    int s[16], d[16];
#pragma unroll
    for (int k = 0; k < 16; ++k) {
        int e = t0 + k * 256;
        if (e < ne) {
            s[k] = __builtin_nontemporal_load(src + e);
            d[k] = __builtin_nontemporal_load(dst + e);
        } else { s[k] = 0; d[k] = -1; }
    }
#pragma unroll
    for (int k = 0; k < 16; ++k)
        if (d[k] >= 0) atomicAdd(&hist[d[k] >> 8], 1);
    __syncthreads();
    for (int i = threadIdx.x; i < nb; i += 256)
        base[i] = (hist[i] > 0) ? atomicAdd(&cursor[i], hist[i]) : 0;
    __syncthreads();
#pragma unroll
    for (int k = 0; k < 16; ++k)
        if (d[k] >= 0) {
            int b = d[k] >> 8;
            int slot = atomicAdd(&base[b], 1);
            int lim = b * CAP + (CAP - 1);
            if (slot > lim) slot = lim;   // overflow guard (never expected)
            bucketBuf[slot] = (s[k] << 8) | (d[k] & 255);
        }
}

// ---- Phase B: counting sort -> csr + pk + dinv + prescaled fp16 x -----------
__global__ void k_bucketB(const int* __restrict__ cursor, const int* __restrict__ bucketBuf,
                          const float* __restrict__ x,
                          int* __restrict__ csr, unsigned* __restrict__ pk,
                          float* __restrict__ dinv, __half* __restrict__ xh, int n) {
    int b = blockIdx.x;
    int beg = b * CAP;
    int cnt = cursor[b] - beg;
    if (cnt > CAP) cnt = CAP;
    __shared__ int hist[256];
    __shared__ int scan[256];
    hist[threadIdx.x] = 0;
    __syncthreads();
    for (int j = threadIdx.x; j < cnt; j += 256)
        atomicAdd(&hist[__builtin_nontemporal_load(bucketBuf + beg + j) & 255], 1);
    __syncthreads();
    int v = hist[threadIdx.x];
    scan[threadIdx.x] = v;
    __syncthreads();
    for (int off = 1; off < 256; off <<= 1) {
        int t = (threadIdx.x >= off) ? scan[threadIdx.x - off] : 0;
        __syncthreads();
        scan[threadIdx.x] += t;
        __syncthreads();
    }
    int excl = scan[threadIdx.x] - v;
    int node = (b << 8) + threadIdx.x;
    if (node < n) {
        pk[node] = (unsigned)(beg + excl) | ((unsigned)v << 22);
        float dd = (float)v + 1.0f;
        float dv = 1.0f / sqrtf(dd);
        dinv[node] = dv;
        // fused padh: xh[node] = dv * x[node], 10 feats zero-padded to 16
        const float* row = x + (size_t)node * 10;
        float vals[16];
#pragma unroll
        for (int k = 0; k < 10; ++k) vals[k] = row[k] * dv;
#pragma unroll
        for (int k = 10; k < 16; ++k) vals[k] = 0.f;
        __half2 out[8];
#pragma unroll
        for (int i = 0; i < 8; ++i) out[i] = __floats2half2_rn(vals[2 * i], vals[2 * i + 1]);
        *(float4*)(xh + (size_t)node * 16)     = *(float4*)(out);
        *(float4*)(xh + (size_t)node * 16 + 8) = *(float4*)(out + 4);
    }
    __syncthreads();
    hist[threadIdx.x] = excl;   // reuse as scatter cursor
    __syncthreads();
    for (int j = threadIdx.x; j < cnt; j += 256) {
        int pkk = __builtin_nontemporal_load(bucketBuf + beg + j);
        int slot = atomicAdd(&hist[pkk & 255], 1);
        csr[beg + slot] = pkk >> 8;
    }
}

// 8 fp16 feats -> add into a0..a7 (dinv folded into table; plain add)
#define CVT8ADD(qq) do { \
    const __half2* hp_ = (const __half2*)&(qq); \
    float2 f0_ = __half22float2(hp_[0]); \
    float2 f1_ = __half22float2(hp_[1]); \
    float2 f2_ = __half22float2(hp_[2]); \
    float2 f3_ = __half22float2(hp_[3]); \
    a0 += f0_.x; a1 += f0_.y; a2 += f1_.x; a3 += f1_.y; \
    a4 += f2_.x; a5 += f2_.y; a6 += f3_.x; a7 += f3_.y; } while (0)

#define RED8(mask) do { \
    a0 += __shfl_xor(a0, mask); a1 += __shfl_xor(a1, mask); \
    a2 += __shfl_xor(a2, mask); a3 += __shfl_xor(a3, mask); \
    a4 += __shfl_xor(a4, mask); a5 += __shfl_xor(a5, mask); \
    a6 += __shfl_xor(a6, mask); a7 += __shfl_xor(a7, mask); } while (0)

// 4-edge-unrolled gather loop over a table of 32 B fp16 rows
#define GATHER_LOOP(tbl) do { \
    int j = beg + q; \
    for (; j + 12 < end; j += 16) { \
        int sA = __builtin_nontemporal_load(csr + j); \
        int sB = __builtin_nontemporal_load(csr + j + 4); \
        int sC = __builtin_nontemporal_load(csr + j + 8); \
        int sD = __builtin_nontemporal_load(csr + j + 12); \
        float4 qA = *(const float4*)((tbl) + (size_t)sA * 16 + half * 8); \
        float4 qB = *(const float4*)((tbl) + (size_t)sB * 16 + half * 8); \
        float4 qC = *(const float4*)((tbl) + (size_t)sC * 16 + half * 8); \
        float4 qD = *(const float4*)((tbl) + (size_t)sD * 16 + half * 8); \
        CVT8ADD(qA); CVT8ADD(qB); CVT8ADD(qC); CVT8ADD(qD); \
    } \
    for (; j < end; j += 4) { \
        int s = __builtin_nontemporal_load(csr + j); \
        float4 qq = *(const float4*)((tbl) + (size_t)s * 16 + half * 8); \
        CVT8ADD(qq); \
    } } while (0)

// lane layout: half = lane&1; edge-slot q = (lane>>1)&3; node-slot = lane>>3

// ---- fused gather1 + lin: mh = prescaled fp16 of relu(z@W1+b1)@W2 -----------
// 32 nodes per block; z lives only in LDS.
__global__ void k_g1lin(const int* __restrict__ csr, const unsigned* __restrict__ pk,
                        const float* __restrict__ dinv, const __half* __restrict__ xh,
                        const float* __restrict__ W1, const float* __restrict__ b1,
                        const float* __restrict__ W2, __half* __restrict__ mh, int n) {
    __shared__ float W1s[640];
    __shared__ float W2s[2048];
    __shared__ float zt[32 * 17];
    __shared__ float hs[32 * 65];
    for (int i = threadIdx.x; i < 640; i += 256)  W1s[i] = W1[i];
    for (int i = threadIdx.x; i < 2048; i += 256) W2s[i] = W2[i];

    int half = threadIdx.x & 1;
    int q = (threadIdx.x >> 1) & 3;
    int slot = threadIdx.x >> 3;
    int v = blockIdx.x * 32 + slot;
    bool valid = (v < n);
    float a0=0.f,a1=0.f,a2=0.f,a3=0.f,a4=0.f,a5=0.f,a6=0.f,a7=0.f;
    if (valid) {
        unsigned p = pk[v];
        int beg = (int)(p & 0x3FFFFFu), end = beg + (int)(p >> 22);
        GATHER_LOOP(xh);
    }
    RED8(2); RED8(4);
    if (q == 0) {
        float o[8] = {0.f,0.f,0.f,0.f,0.f,0.f,0.f,0.f};
        if (valid) {
            float dv = dinv[v];
            float4 qs = *(const float4*)(xh + (size_t)v * 16 + half * 8);
            const __half2* sp = (const __half2*)&qs;
            float2 s0 = __half22float2(sp[0]), s1 = __half22float2(sp[1]);
            float2 s2 = __half22float2(sp[2]), s3 = __half22float2(sp[3]);
            o[0] = (a0 + s0.x) * dv; o[1] = (a1 + s0.y) * dv;
            o[2] = (a2 + s1.x) * dv; o[3] = (a3 + s1.y) * dv;
            o[4] = (a4 + s2.x) * dv; o[5] = (a5 + s2.y) * dv;
            o[6] = (a6 + s3.x) * dv; o[7] = (a7 + s3.y) * dv;
        }
        float* zr = zt + slot * 17 + half * 8;
#pragma unroll
        for (int i = 0; i < 8; ++i) zr[i] = o[i];
    }
    __syncthreads();
    // h1 phase: 32 nodes x 64 feats / 256 threads -> 8 feats each
    {
        int node = threadIdx.x & 31, w = threadIdx.x >> 5;
        float zreg[10];
#pragma unroll
        for (int k = 0; k < 10; ++k) zreg[k] = zt[node * 17 + k];
#pragma unroll
        for (int fq = 0; fq < 8; ++fq) {
            int f = w * 8 + fq;
            float s = b1[f];
#pragma unroll
            for (int k = 0; k < 10; ++k) s += zreg[k] * W1s[k * 64 + f];
            hs[node * 65 + f] = fmaxf(s, 0.f);
        }
    }
    __syncthreads();
    // m phase: 32 nodes x 32 outs / 256 threads -> 4 nodes each
    {
        int o = threadIdx.x & 31, grp = threadIdx.x >> 5;
        int c = o >> 4, within = o & 15;
#pragma unroll
        for (int it = 0; it < 4; ++it) {
            int node = it * 8 + grp;
            int vv = blockIdx.x * 32 + node;
            if (vv < n) {
                float s = 0.f;
#pragma unroll
                for (int f = 0; f < 64; ++f) s += hs[node * 65 + f] * W2s[f * 32 + o];
                mh[((size_t)c * n + vv) * 16 + within] = __float2half(s * dinv[vv]);
            }
        }
    }
}

// ---- gather2 one chunk + relu + per-node FC dot + scalar pool ---------------
__global__ void k_gath2(const int* __restrict__ csr, const unsigned* __restrict__ pk,
                        const float* __restrict__ dinv, const __half* __restrict__ mhc,
                        const float* __restrict__ b2c, const float* __restrict__ wfcc,
                        const int* __restrict__ batch, float* __restrict__ pooledS, int n) {
    int half = threadIdx.x & 1;
    int q = (threadIdx.x >> 1) & 3;
    int v = blockIdx.x * 32 + (threadIdx.x >> 3);
    bool valid = (v < n);
    float a0=0.f,a1=0.f,a2=0.f,a3=0.f,a4=0.f,a5=0.f,a6=0.f,a7=0.f;
    int b = -1;
    if (valid) {
        unsigned p = pk[v];
        int beg = (int)(p & 0x3FFFFFu), end = beg + (int)(p >> 22);
        GATHER_LOOP(mhc);
        b = batch[v];
    }
    RED8(2); RED8(4);
    float part = 0.f;
    if (valid && q == 0) {
        float dv = dinv[v];
        float4 qs = *(const float4*)(mhc + (size_t)v * 16 + half * 8);
        const __half2* sp = (const __half2*)&qs;
        float2 s0 = __half22float2(sp[0]), s1 = __half22float2(sp[1]);
        float2 s2 = __half22float2(sp[2]), s3 = __half22float2(sp[3]);
        const float* bb = b2c + half * 8;
        const float* wf = wfcc + half * 8;
        part  = fmaxf((a0 + s0.x) * dv + bb[0], 0.f) * wf[0];
        part += fmaxf((a1 + s0.y) * dv + bb[1], 0.f) * wf[1];
        part += fmaxf((a2 + s1.x) * dv + bb[2], 0.f) * wf[2];
        part += fmaxf((a3 + s1.y) * dv + bb[3], 0.f) * wf[3];
        part += fmaxf((a4 + s2.x) * dv + bb[4], 0.f) * wf[4];
        part += fmaxf((a5 + s2.y) * dv + bb[5], 0.f) * wf[5];
        part += fmaxf((a6 + s3.x) * dv + bb[6], 0.f) * wf[6];
        part += fmaxf((a7 + s3.y) * dv + bb[7], 0.f) * wf[7];
    }
    // fold half-lanes -> node scalar t[v] on q==0 lanes (both halves hold t)
    part += __shfl_xor(part, 1);
    int b0 = __shfl(b, 0);
    bool uni = __all(!valid || b == b0);
    if (uni) {
        // butterfly over node slots; lane 0's partner set {0,8,...,56} counts
        // each node's t exactly once.
        part += __shfl_xor(part, 8);
        part += __shfl_xor(part, 16);
        part += __shfl_xor(part, 32);
        if ((threadIdx.x & 63) == 0 && b0 >= 0) {
            atomicAdd(pooledS + b0, part);
        }
    } else if (valid && q == 0 && half == 0) {
        atomicAdd(pooledS + b, part);
    }
}

// ---- out[g] = sigmoid(pooledS[g] + bfc) -------------------------------------
__global__ void k_fc(const float* __restrict__ pooledS, const float* __restrict__ bfc,
                     float* __restrict__ out) {
    int g = blockIdx.x * blockDim.x + threadIdx.x;
    if (g < N_GRAPHS) out[g] = 1.0f / (1.0f + expf(-(pooledS[g] + bfc[0])));
}

extern "C" void kernel_launch(void* const* d_in, const int* in_sizes, int n_in,
                              void* d_out, int out_size, void* d_ws, size_t ws_size,
                              hipStream_t stream) {
    const int n  = in_sizes[0] / 10;   // 100000 nodes
    const int ne = in_sizes[1] / 2;    // 1600000 edges
    const int nb = (n + 255) >> 8;     // 391 buckets

    const float* x     = (const float*)d_in[0];
    const int*   ei    = (const int*)d_in[1];
    const int*   batch = (const int*)d_in[2];
    const float* W1    = (const float*)d_in[3];
    const float* b1    = (const float*)d_in[4];
    const float* W2    = (const float*)d_in[5];
    const float* b2    = (const float*)d_in[6];
    const float* Wfc   = (const float*)d_in[7];
    const float* bfc   = (const float*)d_in[8];
    const int* srcp = ei;
    const int* dstp = ei + ne;

    // workspace layout
    char* base = (char*)d_ws;
    size_t off = 0;
    auto take = [&](size_t bytes) { void* p = base + off; off = align_up(off + bytes, 16); return p; };
    int*      cursor    = (int*)     take((size_t)nb * 4);
    int*      bucketBuf = (int*)     take((size_t)nb * CAP * 4);
    int*      csr       = (int*)     take((size_t)nb * CAP * 4);
    unsigned* pk        = (unsigned*)take((size_t)n * 4);
    float*    dinv      = (float*)   take((size_t)n * 4);
    __half*   xh        = (__half*)  take((size_t)n * 16 * 2);
    __half*   mh        = (__half*)  take((size_t)n * 32 * 2);   // [2][n][16]
    float*    pooledS   = (float*)   take((size_t)N_GRAPHS * 4);

    k_init   <<<4, 256, 0, stream>>>(cursor, pooledS, nb);
    k_bucketA<<<(ne + TILE_A - 1) / TILE_A, 256, 0, stream>>>(srcp, dstp, cursor, bucketBuf, ne, nb);
    k_bucketB<<<nb, 256, 0, stream>>>(cursor, bucketBuf, x, csr, pk, dinv, xh, n);
    k_g1lin  <<<(n + 31) / 32, 256, 0, stream>>>(csr, pk, dinv, xh, W1, b1, W2, mh, n);
    k_gath2  <<<(n + 31) / 32, 256, 0, stream>>>(csr, pk, dinv, mh,
                                                 b2, Wfc, batch, pooledS, n);
    k_gath2  <<<(n + 31) / 32, 256, 0, stream>>>(csr, pk, dinv, mh + (size_t)n * 16,
                                                 b2 + 16, Wfc + 16, batch, pooledS, n);
    k_fc     <<<2, 256, 0, stream>>>(pooledS, bfc, (float*)d_out);
}

// Round 13
// 144.883 us; speedup vs baseline: 1.7985x; 1.0820x over previous
//
#include <hip/hip_runtime.h>
#include <hip/hip_fp16.h>
#include <math.h>

#define N_GRAPHS 512
#define CAP 5120          // bucket capacity: mean 4096, sigma 64
#define TILE_A 4096       // edges per phase-A workgroup (16/thread)

static inline size_t align_up(size_t v, size_t a) { return (v + a - 1) / a * a; }

// ---- init: bucket cursors + zero scalar pooled ------------------------------
__global__ void k_init(int* __restrict__ cursor, float* __restrict__ pooledS, int nb) {
    int i = blockIdx.x * blockDim.x + threadIdx.x;
    if (i < nb) cursor[i] = i * CAP;
    if (i < N_GRAPHS) pooledS[i] = 0.f;
}

// ---- Phase A: partition edges into dst-range buckets ------------------------
__global__ void k_bucketA(const int* __restrict__ src, const int* __restrict__ dst,
                          int* __restrict__ cursor, int* __restrict__ bucketBuf,
                          int ne, int nb) {
    __shared__ int hist[512];
    __shared__ int base[512];
    for (int i = threadIdx.x; i < nb; i += 256) hist[i] = 0;
    __syncthreads();
    int t0 = blockIdx.x * TILE_A + threadIdx.x;
    int s[16], d[16];
#pragma unroll
    for (int k = 0; k < 16; ++k) {
        int e = t0 + k * 256;
        if (e < ne) {
            s[k] = __builtin_nontemporal_load(src + e);
            d[k] = __builtin_nontemporal_load(dst + e);
        } else { s[k] = 0; d[k] = -1; }
    }
#pragma unroll
    for (int k = 0; k < 16; ++k)
        if (d[k] >= 0) atomicAdd(&hist[d[k] >> 8], 1);
    __syncthreads();
    for (int i = threadIdx.x; i < nb; i += 256)
        base[i] = (hist[i] > 0) ? atomicAdd(&cursor[i], hist[i]) : 0;
    __syncthreads();
#pragma unroll
    for (int k = 0; k < 16; ++k)
        if (d[k] >= 0) {
            int b = d[k] >> 8;
            int slot = atomicAdd(&base[b], 1);
            int lim = b * CAP + (CAP - 1);
            if (slot > lim) slot = lim;   // overflow guard (never expected)
            bucketBuf[slot] = (s[k] << 8) | (d[k] & 255);
        }
}

// ---- Phase B: counting sort -> csr + pk + dinv + prescaled fp32 x [n][16] ---
__global__ void k_bucketB(const int* __restrict__ cursor, const int* __restrict__ bucketBuf,
                          const float* __restrict__ x,
                          int* __restrict__ csr, unsigned* __restrict__ pk,
                          float* __restrict__ dinv, float* __restrict__ xq, int n) {
    int b = blockIdx.x;
    int beg = b * CAP;
    int cnt = cursor[b] - beg;
    if (cnt > CAP) cnt = CAP;
    __shared__ int hist[256];
    __shared__ int scan[256];
    hist[threadIdx.x] = 0;
    __syncthreads();
    for (int j = threadIdx.x; j < cnt; j += 256)
        atomicAdd(&hist[__builtin_nontemporal_load(bucketBuf + beg + j) & 255], 1);
    __syncthreads();
    int v = hist[threadIdx.x];
    scan[threadIdx.x] = v;
    __syncthreads();
    for (int off = 1; off < 256; off <<= 1) {
        int t = (threadIdx.x >= off) ? scan[threadIdx.x - off] : 0;
        __syncthreads();
        scan[threadIdx.x] += t;
        __syncthreads();
    }
    int excl = scan[threadIdx.x] - v;
    int node = (b << 8) + threadIdx.x;
    if (node < n) {
        pk[node] = (unsigned)(beg + excl) | ((unsigned)v << 22);
        float dd = (float)v + 1.0f;
        float dv = 1.0f / sqrtf(dd);
        dinv[node] = dv;
        // fused pad: xq[node] = dv * x[node], 10 feats zero-padded to 16 (fp32)
        const float* row = x + (size_t)node * 10;
        float vals[16];
#pragma unroll
        for (int k = 0; k < 10; ++k) vals[k] = row[k] * dv;
#pragma unroll
        for (int k = 10; k < 16; ++k) vals[k] = 0.f;
        float* outp = xq + (size_t)node * 16;
#pragma unroll
        for (int i = 0; i < 4; ++i)
            *(float4*)(outp + i * 4) = *(float4*)(vals + i * 4);
    }
    __syncthreads();
    hist[threadIdx.x] = excl;   // reuse as scatter cursor
    __syncthreads();
    for (int j = threadIdx.x; j < cnt; j += 256) {
        int pkk = __builtin_nontemporal_load(bucketBuf + beg + j);
        int slot = atomicAdd(&hist[pkk & 255], 1);
        csr[beg + slot] = pkk >> 8;
    }
}

// lane layout (both gathers): quarter = lane&3 (16 B of the 64 B row),
// q = (lane>>2)&1 (edge slot, stride 2), node slot = lane>>3 (8 nodes/wave)

// 8 fp16 feats -> add into a0..a7
#define CVT8ADD(qq) do { \
    const __half2* hp_ = (const __half2*)&(qq); \
    float2 f0_ = __half22float2(hp_[0]); \
    float2 f1_ = __half22float2(hp_[1]); \
    float2 f2_ = __half22float2(hp_[2]); \
    float2 f3_ = __half22float2(hp_[3]); \
    a0 += f0_.x; a1 += f0_.y; a2 += f1_.x; a3 += f1_.y; \
    a4 += f2_.x; a5 += f2_.y; a6 += f3_.x; a7 += f3_.y; } while (0)

#define RED8(mask) do { \
    a0 += __shfl_xor(a0, mask); a1 += __shfl_xor(a1, mask); \
    a2 += __shfl_xor(a2, mask); a3 += __shfl_xor(a3, mask); \
    a4 += __shfl_xor(a4, mask); a5 += __shfl_xor(a5, mask); \
    a6 += __shfl_xor(a6, mask); a7 += __shfl_xor(a7, mask); } while (0)

// ---- fused gather1 + MLP: mh = fp16(dinv * (relu(z@W1+b1)@W2))  [n][32] -----
// 64 nodes per 512-thread block; z lives only in LDS; x table fp32 [n][16].
__global__ void k_g1lin(const int* __restrict__ csr, const unsigned* __restrict__ pk,
                        const float* __restrict__ dinv, const float* __restrict__ xq,
                        const float* __restrict__ W1, const float* __restrict__ b1,
                        const float* __restrict__ W2, __half* __restrict__ mh, int n) {
    __shared__ float W1s[640];
    __shared__ float W2s[2048];
    __shared__ float zt[64 * 17];
    __shared__ float hs[64 * 65];
    for (int i = threadIdx.x; i < 640; i += 512)  W1s[i] = W1[i];
    for (int i = threadIdx.x; i < 2048; i += 512) W2s[i] = W2[i];

    int quarter = threadIdx.x & 3;
    int q = (threadIdx.x >> 2) & 1;
    int slot = threadIdx.x >> 3;                 // 0..63
    int v = blockIdx.x * 64 + slot;
    bool valid = (v < n);
    float4 acc = make_float4(0.f, 0.f, 0.f, 0.f);
    if (valid) {
        unsigned p = pk[v];
        int beg = (int)(p & 0x3FFFFFu), end = beg + (int)(p >> 22);
        int j = beg + q;
        for (; j + 6 < end; j += 8) {
            int sA = __builtin_nontemporal_load(csr + j);
            int sB = __builtin_nontemporal_load(csr + j + 2);
            int sC = __builtin_nontemporal_load(csr + j + 4);
            int sD = __builtin_nontemporal_load(csr + j + 6);
            float4 rA = *(const float4*)(xq + (size_t)sA * 16 + quarter * 4);
            float4 rB = *(const float4*)(xq + (size_t)sB * 16 + quarter * 4);
            float4 rC = *(const float4*)(xq + (size_t)sC * 16 + quarter * 4);
            float4 rD = *(const float4*)(xq + (size_t)sD * 16 + quarter * 4);
            acc.x += rA.x + rB.x + rC.x + rD.x;
            acc.y += rA.y + rB.y + rC.y + rD.y;
            acc.z += rA.z + rB.z + rC.z + rD.z;
            acc.w += rA.w + rB.w + rC.w + rD.w;
        }
        for (; j < end; j += 2) {
            int s = __builtin_nontemporal_load(csr + j);
            float4 r = *(const float4*)(xq + (size_t)s * 16 + quarter * 4);
            acc.x += r.x; acc.y += r.y; acc.z += r.z; acc.w += r.w;
        }
    }
    // fold edge-slot q (mask 4)
    acc.x += __shfl_xor(acc.x, 4); acc.y += __shfl_xor(acc.y, 4);
    acc.z += __shfl_xor(acc.z, 4); acc.w += __shfl_xor(acc.w, 4);
    if (q == 0) {
        float4 o = make_float4(0.f, 0.f, 0.f, 0.f);
        if (valid) {
            float dv = dinv[v];
            float4 sv = *(const float4*)(xq + (size_t)v * 16 + quarter * 4);
            o.x = (acc.x + sv.x) * dv; o.y = (acc.y + sv.y) * dv;
            o.z = (acc.z + sv.z) * dv; o.w = (acc.w + sv.w) * dv;
        }
        float* zr = zt + slot * 17 + quarter * 4;
        zr[0] = o.x; zr[1] = o.y; zr[2] = o.z; zr[3] = o.w;
    }
    __syncthreads();
    // h1 phase: 64 nodes x 64 feats / 512 threads -> 8 feats each
    {
        int node = threadIdx.x & 63, w = threadIdx.x >> 6;
        float zreg[10];
#pragma unroll
        for (int k = 0; k < 10; ++k) zreg[k] = zt[node * 17 + k];
#pragma unroll
        for (int fq = 0; fq < 8; ++fq) {
            int f = w * 8 + fq;
            float s = b1[f];
#pragma unroll
            for (int k = 0; k < 10; ++k) s += zreg[k] * W1s[k * 64 + f];
            hs[node * 65 + f] = fmaxf(s, 0.f);
        }
    }
    __syncthreads();
    // m phase: 64 nodes x 32 outs / 512 threads -> 4 outputs each
    {
        int o = threadIdx.x & 31, grp = threadIdx.x >> 5;   // 16 groups
#pragma unroll
        for (int it = 0; it < 4; ++it) {
            int node = it * 16 + grp;
            int vv = blockIdx.x * 64 + node;
            if (vv < n) {
                float s = 0.f;
#pragma unroll
                for (int f = 0; f < 64; ++f) s += hs[node * 65 + f] * W2s[f * 32 + o];
                mh[(size_t)vv * 32 + o] = __float2half(s * dinv[vv]);
            }
        }
    }
}

// ---- gather2 single pass (32 fp16 feats, 64 B rows) + relu + FC + pool ------
__global__ void k_gath2(const int* __restrict__ csr, const unsigned* __restrict__ pk,
                        const float* __restrict__ dinv, const __half* __restrict__ mh,
                        const float* __restrict__ b2, const float* __restrict__ Wfc,
                        const int* __restrict__ batch, float* __restrict__ pooledS, int n) {
    int quarter = threadIdx.x & 3;
    int q = (threadIdx.x >> 2) & 1;
    int v = blockIdx.x * 32 + (threadIdx.x >> 3);
    bool valid = (v < n);
    float a0=0.f,a1=0.f,a2=0.f,a3=0.f,a4=0.f,a5=0.f,a6=0.f,a7=0.f;
    int b = -1;
    if (valid) {
        unsigned p = pk[v];
        int beg = (int)(p & 0x3FFFFFu), end = beg + (int)(p >> 22);
        int j = beg + q;
        for (; j + 6 < end; j += 8) {
            int sA = __builtin_nontemporal_load(csr + j);
            int sB = __builtin_nontemporal_load(csr + j + 2);
            int sC = __builtin_nontemporal_load(csr + j + 4);
            int sD = __builtin_nontemporal_load(csr + j + 6);
            float4 qA = *(const float4*)(mh + (size_t)sA * 32 + quarter * 8);
            float4 qB = *(const float4*)(mh + (size_t)sB * 32 + quarter * 8);
            float4 qC = *(const float4*)(mh + (size_t)sC * 32 + quarter * 8);
            float4 qD = *(const float4*)(mh + (size_t)sD * 32 + quarter * 8);
            CVT8ADD(qA); CVT8ADD(qB); CVT8ADD(qC); CVT8ADD(qD);
        }
        for (; j < end; j += 2) {
            int s = __builtin_nontemporal_load(csr + j);
            float4 qq = *(const float4*)(mh + (size_t)s * 32 + quarter * 8);
            CVT8ADD(qq);
        }
        b = batch[v];
    }
    RED8(4);   // fold edge-slot q; now all 8 lanes of a node hold their quarter's sums
    float part = 0.f;
    if (valid) {
        float dv = dinv[v];
        float4 qs = *(const float4*)(mh + (size_t)v * 32 + quarter * 8);
        const __half2* sp = (const __half2*)&qs;
        float2 s0 = __half22float2(sp[0]), s1 = __half22float2(sp[1]);
        float2 s2 = __half22float2(sp[2]), s3 = __half22float2(sp[3]);
        const float* bb = b2 + quarter * 8;
        const float* wf = Wfc + quarter * 8;
        part  = fmaxf((a0 + s0.x) * dv + bb[0], 0.f) * wf[0];
        part += fmaxf((a1 + s0.y) * dv + bb[1], 0.f) * wf[1];
        part += fmaxf((a2 + s1.x) * dv + bb[2], 0.f) * wf[2];
        part += fmaxf((a3 + s1.y) * dv + bb[3], 0.f) * wf[3];
        part += fmaxf((a4 + s2.x) * dv + bb[4], 0.f) * wf[4];
        part += fmaxf((a5 + s2.y) * dv + bb[5], 0.f) * wf[5];
        part += fmaxf((a6 + s3.x) * dv + bb[6], 0.f) * wf[6];
        part += fmaxf((a7 + s3.y) * dv + bb[7], 0.f) * wf[7];
    }
    // fold quarters (masks 1,2): every lane of the node now holds t[v]
    part += __shfl_xor(part, 1);
    part += __shfl_xor(part, 2);
    int b0 = __shfl(b, 0);
    bool uni = __all(!valid || b == b0);
    if (uni) {
        // butterfly over node slots: lane 0's partner set {0,8,...,56} counts
        // each node's t exactly once.
        part += __shfl_xor(part, 8);
        part += __shfl_xor(part, 16);
        part += __shfl_xor(part, 32);
        if ((threadIdx.x & 63) == 0 && b0 >= 0) {
            atomicAdd(pooledS + b0, part);
        }
    } else if (valid && (threadIdx.x & 7) == 0) {
        atomicAdd(pooledS + b, part);
    }
}

// ---- out[g] = sigmoid(pooledS[g] + bfc) -------------------------------------
__global__ void k_fc(const float* __restrict__ pooledS, const float* __restrict__ bfc,
                     float* __restrict__ out) {
    int g = blockIdx.x * blockDim.x + threadIdx.x;
    if (g < N_GRAPHS) out[g] = 1.0f / (1.0f + expf(-(pooledS[g] + bfc[0])));
}

extern "C" void kernel_launch(void* const* d_in, const int* in_sizes, int n_in,
                              void* d_out, int out_size, void* d_ws, size_t ws_size,
                              hipStream_t stream) {
    const int n  = in_sizes[0] / 10;   // 100000 nodes
    const int ne = in_sizes[1] / 2;    // 1600000 edges
    const int nb = (n + 255) >> 8;     // 391 buckets

    const float* x     = (const float*)d_in[0];
    const int*   ei    = (const int*)d_in[1];
    const int*   batch = (const int*)d_in[2];
    const float* W1    = (const float*)d_in[3];
    const float* b1    = (const float*)d_in[4];
    const float* W2    = (const float*)d_in[5];
    const float* b2    = (const float*)d_in[6];
    const float* Wfc   = (const float*)d_in[7];
    const float* bfc   = (const float*)d_in[8];
    const int* srcp = ei;
    const int* dstp = ei + ne;

    // workspace layout
    char* base = (char*)d_ws;
    size_t off = 0;
    auto take = [&](size_t bytes) { void* p = base + off; off = align_up(off + bytes, 16); return p; };
    int*      cursor    = (int*)     take((size_t)nb * 4);
    int*      bucketBuf = (int*)     take((size_t)nb * CAP * 4);
    int*      csr       = (int*)     take((size_t)nb * CAP * 4);
    unsigned* pk        = (unsigned*)take((size_t)n * 4);
    float*    dinv      = (float*)   take((size_t)n * 4);
    float*    xq        = (float*)   take((size_t)n * 16 * 4);
    __half*   mh        = (__half*)  take((size_t)n * 32 * 2);   // [n][32]
    float*    pooledS   = (float*)   take((size_t)N_GRAPHS * 4);

    k_init   <<<4, 256, 0, stream>>>(cursor, pooledS, nb);
    k_bucketA<<<(ne + TILE_A - 1) / TILE_A, 256, 0, stream>>>(srcp, dstp, cursor, bucketBuf, ne, nb);
    k_bucketB<<<nb, 256, 0, stream>>>(cursor, bucketBuf, x, csr, pk, dinv, xq, n);
    k_g1lin  <<<(n + 63) / 64, 512, 0, stream>>>(csr, pk, dinv, xq, W1, b1, W2, mh, n);
    k_gath2  <<<(n + 31) / 32, 256, 0, stream>>>(csr, pk, dinv, mh,
                                                 b2, Wfc, batch, pooledS, n);
    k_fc     <<<2, 256, 0, stream>>>(pooledS, bfc, (float*)d_out);
}

// Round 14
// 133.418 us; speedup vs baseline: 1.9530x; 1.0859x over previous
//
#include <hip/hip_runtime.h>
#include <hip/hip_fp16.h>
#include <math.h>

#define N_GRAPHS 512
#define CAP 5120          // bucket capacity: mean 4096, sigma 64
#define TILE_A 4096       // edges per phase-A workgroup (16/thread)

static inline size_t align_up(size_t v, size_t a) { return (v + a - 1) / a * a; }

// ---- init: bucket cursors + zero scalar pooled ------------------------------
__global__ void k_init(int* __restrict__ cursor, float* __restrict__ pooledS, int nb) {
    int i = blockIdx.x * blockDim.x + threadIdx.x;
    if (i < nb) cursor[i] = i * CAP;
    if (i < N_GRAPHS) pooledS[i] = 0.f;
}

// ---- Phase A: partition edges into dst-range buckets ------------------------
__global__ void k_bucketA(const int* __restrict__ src, const int* __restrict__ dst,
                          int* __restrict__ cursor, int* __restrict__ bucketBuf,
                          int ne, int nb) {
    __shared__ int hist[512];
    __shared__ int base[512];
    for (int i = threadIdx.x; i < nb; i += 256) hist[i] = 0;
    __syncthreads();
    int t0 = blockIdx.x * TILE_A + threadIdx.x;
    int s[16], d[16];
#pragma unroll
    for (int k = 0; k < 16; ++k) {
        int e = t0 + k * 256;
        if (e < ne) {
            s[k] = __builtin_nontemporal_load(src + e);
            d[k] = __builtin_nontemporal_load(dst + e);
        } else { s[k] = 0; d[k] = -1; }
    }
#pragma unroll
    for (int k = 0; k < 16; ++k)
        if (d[k] >= 0) atomicAdd(&hist[d[k] >> 8], 1);
    __syncthreads();
    for (int i = threadIdx.x; i < nb; i += 256)
        base[i] = (hist[i] > 0) ? atomicAdd(&cursor[i], hist[i]) : 0;
    __syncthreads();
#pragma unroll
    for (int k = 0; k < 16; ++k)
        if (d[k] >= 0) {
            int b = d[k] >> 8;
            int slot = atomicAdd(&base[b], 1);
            int lim = b * CAP + (CAP - 1);
            if (slot > lim) slot = lim;   // overflow guard (never expected)
            bucketBuf[slot] = (s[k] << 8) | (d[k] & 255);
        }
}

// ---- Phase B: counting sort -> csr + pk + dinv + prescaled fp16 x [n][16] ---
__global__ void k_bucketB(const int* __restrict__ cursor, const int* __restrict__ bucketBuf,
                          const float* __restrict__ x,
                          int* __restrict__ csr, unsigned* __restrict__ pk,
                          float* __restrict__ dinv, __half* __restrict__ xh, int n) {
    int b = blockIdx.x;
    int beg = b * CAP;
    int cnt = cursor[b] - beg;
    if (cnt > CAP) cnt = CAP;
    __shared__ int hist[256];
    __shared__ int scan[256];
    hist[threadIdx.x] = 0;
    __syncthreads();
    for (int j = threadIdx.x; j < cnt; j += 256)
        atomicAdd(&hist[__builtin_nontemporal_load(bucketBuf + beg + j) & 255], 1);
    __syncthreads();
    int v = hist[threadIdx.x];
    scan[threadIdx.x] = v;
    __syncthreads();
    for (int off = 1; off < 256; off <<= 1) {
        int t = (threadIdx.x >= off) ? scan[threadIdx.x - off] : 0;
        __syncthreads();
        scan[threadIdx.x] += t;
        __syncthreads();
    }
    int excl = scan[threadIdx.x] - v;
    int node = (b << 8) + threadIdx.x;
    if (node < n) {
        pk[node] = (unsigned)(beg + excl) | ((unsigned)v << 22);
        float dd = (float)v + 1.0f;
        float dv = 1.0f / sqrtf(dd);
        dinv[node] = dv;
        // fused pad: xh[node] = dv * x[node], 10 feats zero-padded to 16 (fp16)
        const float* row = x + (size_t)node * 10;
        float vals[16];
#pragma unroll
        for (int k = 0; k < 10; ++k) vals[k] = row[k] * dv;
#pragma unroll
        for (int k = 10; k < 16; ++k) vals[k] = 0.f;
        __half2 out[8];
#pragma unroll
        for (int i = 0; i < 8; ++i) out[i] = __floats2half2_rn(vals[2 * i], vals[2 * i + 1]);
        *(float4*)(xh + (size_t)node * 16)     = *(float4*)(out);
        *(float4*)(xh + (size_t)node * 16 + 8) = *(float4*)(out + 4);
    }
    __syncthreads();
    hist[threadIdx.x] = excl;   // reuse as scatter cursor
    __syncthreads();
    for (int j = threadIdx.x; j < cnt; j += 256) {
        int pkk = __builtin_nontemporal_load(bucketBuf + beg + j);
        int slot = atomicAdd(&hist[pkk & 255], 1);
        csr[beg + slot] = pkk >> 8;
    }
}

// 8 fp16 feats -> add into a0..a7
#define CVT8ADD(qq) do { \
    const __half2* hp_ = (const __half2*)&(qq); \
    float2 f0_ = __half22float2(hp_[0]); \
    float2 f1_ = __half22float2(hp_[1]); \
    float2 f2_ = __half22float2(hp_[2]); \
    float2 f3_ = __half22float2(hp_[3]); \
    a0 += f0_.x; a1 += f0_.y; a2 += f1_.x; a3 += f1_.y; \
    a4 += f2_.x; a5 += f2_.y; a6 += f3_.x; a7 += f3_.y; } while (0)

#define RED8(mask) do { \
    a0 += __shfl_xor(a0, mask); a1 += __shfl_xor(a1, mask); \
    a2 += __shfl_xor(a2, mask); a3 += __shfl_xor(a3, mask); \
    a4 += __shfl_xor(a4, mask); a5 += __shfl_xor(a5, mask); \
    a6 += __shfl_xor(a6, mask); a7 += __shfl_xor(a7, mask); } while (0)

// 4-edge-unrolled gather loop over a table of 32 B fp16 rows
// lane layout: half = lane&1; edge-slot q = (lane>>1)&3; node slot = lane>>3
#define GATHER_LOOP16(tbl) do { \
    int j = beg + q; \
    for (; j + 12 < end; j += 16) { \
        int sA = __builtin_nontemporal_load(csr + j); \
        int sB = __builtin_nontemporal_load(csr + j + 4); \
        int sC = __builtin_nontemporal_load(csr + j + 8); \
        int sD = __builtin_nontemporal_load(csr + j + 12); \
        float4 qA = *(const float4*)((tbl) + (size_t)sA * 16 + half * 8); \
        float4 qB = *(const float4*)((tbl) + (size_t)sB * 16 + half * 8); \
        float4 qC = *(const float4*)((tbl) + (size_t)sC * 16 + half * 8); \
        float4 qD = *(const float4*)((tbl) + (size_t)sD * 16 + half * 8); \
        CVT8ADD(qA); CVT8ADD(qB); CVT8ADD(qC); CVT8ADD(qD); \
    } \
    for (; j < end; j += 4) { \
        int s = __builtin_nontemporal_load(csr + j); \
        float4 qq = *(const float4*)((tbl) + (size_t)s * 16 + half * 8); \
        CVT8ADD(qq); \
    } } while (0)

// ---- fused gather1 + MLP: mh = fp16(dinv * (relu(z@W1+b1)@W2))  [n][32] -----
// 64 nodes per 512-thread block; z only in LDS; x table fp16 [n][16] (3.2 MB).
__global__ void k_g1lin(const int* __restrict__ csr, const unsigned* __restrict__ pk,
                        const float* __restrict__ dinv, const __half* __restrict__ xh,
                        const float* __restrict__ W1, const float* __restrict__ b1,
                        const float* __restrict__ W2, __half* __restrict__ mh, int n) {
    __shared__ float W1s[640];
    __shared__ float W2s[2048];
    __shared__ float zt[64 * 17];
    __shared__ float hs[64 * 65];
    for (int i = threadIdx.x; i < 640; i += 512)  W1s[i] = W1[i];
    for (int i = threadIdx.x; i < 2048; i += 512) W2s[i] = W2[i];

    int half = threadIdx.x & 1;
    int q = (threadIdx.x >> 1) & 3;
    int slot = threadIdx.x >> 3;                 // 0..63
    int v = blockIdx.x * 64 + slot;
    bool valid = (v < n);
    float a0=0.f,a1=0.f,a2=0.f,a3=0.f,a4=0.f,a5=0.f,a6=0.f,a7=0.f;
    if (valid) {
        unsigned p = pk[v];
        int beg = (int)(p & 0x3FFFFFu), end = beg + (int)(p >> 22);
        GATHER_LOOP16(xh);
    }
    RED8(2); RED8(4);
    if (q == 0) {
        float o[8] = {0.f,0.f,0.f,0.f,0.f,0.f,0.f,0.f};
        if (valid) {
            float dv = dinv[v];
            float4 qs = *(const float4*)(xh + (size_t)v * 16 + half * 8);
            const __half2* sp = (const __half2*)&qs;
            float2 s0 = __half22float2(sp[0]), s1 = __half22float2(sp[1]);
            float2 s2 = __half22float2(sp[2]), s3 = __half22float2(sp[3]);
            o[0] = (a0 + s0.x) * dv; o[1] = (a1 + s0.y) * dv;
            o[2] = (a2 + s1.x) * dv; o[3] = (a3 + s1.y) * dv;
            o[4] = (a4 + s2.x) * dv; o[5] = (a5 + s2.y) * dv;
            o[6] = (a6 + s3.x) * dv; o[7] = (a7 + s3.y) * dv;
        }
        float* zr = zt + slot * 17 + half * 8;
#pragma unroll
        for (int i = 0; i < 8; ++i) zr[i] = o[i];
    }
    __syncthreads();
    // h1 phase: 64 nodes x 64 feats / 512 threads -> 8 feats each
    {
        int node = threadIdx.x & 63, w = threadIdx.x >> 6;
        float zreg[10];
#pragma unroll
        for (int k = 0; k < 10; ++k) zreg[k] = zt[node * 17 + k];
#pragma unroll
        for (int fq = 0; fq < 8; ++fq) {
            int f = w * 8 + fq;
            float s = b1[f];
#pragma unroll
            for (int k = 0; k < 10; ++k) s += zreg[k] * W1s[k * 64 + f];
            hs[node * 65 + f] = fmaxf(s, 0.f);
        }
    }
    __syncthreads();
    // m phase: 64 nodes x 32 outs / 512 threads -> 4 outputs each
    {
        int o = threadIdx.x & 31, grp = threadIdx.x >> 5;   // 16 groups
#pragma unroll
        for (int it = 0; it < 4; ++it) {
            int node = it * 16 + grp;
            int vv = blockIdx.x * 64 + node;
            if (vv < n) {
                float s = 0.f;
#pragma unroll
                for (int f = 0; f < 64; ++f) s += hs[node * 65 + f] * W2s[f * 32 + o];
                mh[(size_t)vv * 32 + o] = __float2half(s * dinv[vv]);
            }
        }
    }
}

// ---- gather2 single pass (32 fp16 feats, 64 B rows) + relu + FC + pool ------
// lane layout: quarter = lane&3; edge-slot q = (lane>>2)&1; node slot = lane>>3
__global__ void k_gath2(const int* __restrict__ csr, const unsigned* __restrict__ pk,
                        const float* __restrict__ dinv, const __half* __restrict__ mh,
                        const float* __restrict__ b2, const float* __restrict__ Wfc,
                        const int* __restrict__ batch, float* __restrict__ pooledS, int n) {
    int quarter = threadIdx.x & 3;
    int q = (threadIdx.x >> 2) & 1;
    int v = blockIdx.x * 32 + (threadIdx.x >> 3);
    bool valid = (v < n);
    float a0=0.f,a1=0.f,a2=0.f,a3=0.f,a4=0.f,a5=0.f,a6=0.f,a7=0.f;
    int b = -1;
    if (valid) {
        unsigned p = pk[v];
        int beg = (int)(p & 0x3FFFFFu), end = beg + (int)(p >> 22);
        int j = beg + q;
        for (; j + 6 < end; j += 8) {
            int sA = __builtin_nontemporal_load(csr + j);
            int sB = __builtin_nontemporal_load(csr + j + 2);
            int sC = __builtin_nontemporal_load(csr + j + 4);
            int sD = __builtin_nontemporal_load(csr + j + 6);
            float4 qA = *(const float4*)(mh + (size_t)sA * 32 + quarter * 8);
            float4 qB = *(const float4*)(mh + (size_t)sB * 32 + quarter * 8);
            float4 qC = *(const float4*)(mh + (size_t)sC * 32 + quarter * 8);
            float4 qD = *(const float4*)(mh + (size_t)sD * 32 + quarter * 8);
            CVT8ADD(qA); CVT8ADD(qB); CVT8ADD(qC); CVT8ADD(qD);
        }
        for (; j < end; j += 2) {
            int s = __builtin_nontemporal_load(csr + j);
            float4 qq = *(const float4*)(mh + (size_t)s * 32 + quarter * 8);
            CVT8ADD(qq);
        }
        b = batch[v];
    }
    RED8(4);   // fold edge-slot q
    float part = 0.f;
    if (valid) {
        float dv = dinv[v];
        float4 qs = *(const float4*)(mh + (size_t)v * 32 + quarter * 8);
        const __half2* sp = (const __half2*)&qs;
        float2 s0 = __half22float2(sp[0]), s1 = __half22float2(sp[1]);
        float2 s2 = __half22float2(sp[2]), s3 = __half22float2(sp[3]);
        const float* bb = b2 + quarter * 8;
        const float* wf = Wfc + quarter * 8;
        part  = fmaxf((a0 + s0.x) * dv + bb[0], 0.f) * wf[0];
        part += fmaxf((a1 + s0.y) * dv + bb[1], 0.f) * wf[1];
        part += fmaxf((a2 + s1.x) * dv + bb[2], 0.f) * wf[2];
        part += fmaxf((a3 + s1.y) * dv + bb[3], 0.f) * wf[3];
        part += fmaxf((a4 + s2.x) * dv + bb[4], 0.f) * wf[4];
        part += fmaxf((a5 + s2.y) * dv + bb[5], 0.f) * wf[5];
        part += fmaxf((a6 + s3.x) * dv + bb[6], 0.f) * wf[6];
        part += fmaxf((a7 + s3.y) * dv + bb[7], 0.f) * wf[7];
    }
    // fold quarters (masks 1,2): every lane of the node now holds t[v]
    part += __shfl_xor(part, 1);
    part += __shfl_xor(part, 2);
    int b0 = __shfl(b, 0);
    bool uni = __all(!valid || b == b0);
    if (uni) {
        // butterfly over node slots: lane 0's partner set {0,8,...,56} counts
        // each node's t exactly once.
        part += __shfl_xor(part, 8);
        part += __shfl_xor(part, 16);
        part += __shfl_xor(part, 32);
        if ((threadIdx.x & 63) == 0 && b0 >= 0) {
            atomicAdd(pooledS + b0, part);
        }
    } else if (valid && (threadIdx.x & 7) == 0) {
        atomicAdd(pooledS + b, part);
    }
}

// ---- out[g] = sigmoid(pooledS[g] + bfc) -------------------------------------
__global__ void k_fc(const float* __restrict__ pooledS, const float* __restrict__ bfc,
                     float* __restrict__ out) {
    int g = blockIdx.x * blockDim.x + threadIdx.x;
    if (g < N_GRAPHS) out[g] = 1.0f / (1.0f + expf(-(pooledS[g] + bfc[0])));
}

extern "C" void kernel_launch(void* const* d_in, const int* in_sizes, int n_in,
                              void* d_out, int out_size, void* d_ws, size_t ws_size,
                              hipStream_t stream) {
    const int n  = in_sizes[0] / 10;   // 100000 nodes
    const int ne = in_sizes[1] / 2;    // 1600000 edges
    const int nb = (n + 255) >> 8;     // 391 buckets

    const float* x     = (const float*)d_in[0];
    const int*   ei    = (const int*)d_in[1];
    const int*   batch = (const int*)d_in[2];
    const float* W1    = (const float*)d_in[3];
    const float* b1    = (const float*)d_in[4];
    const float* W2    = (const float*)d_in[5];
    const float* b2    = (const float*)d_in[6];
    const float* Wfc   = (const float*)d_in[7];
    const float* bfc   = (const float*)d_in[8];
    const int* srcp = ei;
    const int* dstp = ei + ne;

    // workspace layout
    char* base = (char*)d_ws;
    size_t off = 0;
    auto take = [&](size_t bytes) { void* p = base + off; off = align_up(off + bytes, 16); return p; };
    int*      cursor    = (int*)     take((size_t)nb * 4);
    int*      bucketBuf = (int*)     take((size_t)nb * CAP * 4);
    int*      csr       = (int*)     take((size_t)nb * CAP * 4);
    unsigned* pk        = (unsigned*)take((size_t)n * 4);
    float*    dinv      = (float*)   take((size_t)n * 4);
    __half*   xh        = (__half*)  take((size_t)n * 16 * 2);
    __half*   mh        = (__half*)  take((size_t)n * 32 * 2);   // [n][32]
    float*    pooledS   = (float*)   take((size_t)N_GRAPHS * 4);

    k_init   <<<4, 256, 0, stream>>>(cursor, pooledS, nb);
    k_bucketA<<<(ne + TILE_A - 1) / TILE_A, 256, 0, stream>>>(srcp, dstp, cursor, bucketBuf, ne, nb);
    k_bucketB<<<nb, 256, 0, stream>>>(cursor, bucketBuf, x, csr, pk, dinv, xh, n);
    k_g1lin  <<<(n + 63) / 64, 512, 0, stream>>>(csr, pk, dinv, xh, W1, b1, W2, mh, n);
    k_gath2  <<<(n + 31) / 32, 256, 0, stream>>>(csr, pk, dinv, mh,
                                                 b2, Wfc, batch, pooledS, n);
    k_fc     <<<2, 256, 0, stream>>>(pooledS, bfc, (float*)d_out);
}

// Round 15
// 121.306 us; speedup vs baseline: 2.1480x; 1.0999x over previous
//
#include <hip/hip_runtime.h>
#include <hip/hip_fp16.h>
#include <math.h>

#define N_GRAPHS 512
#define CAP 5120          // bucket capacity: mean 4096, sigma 64
#define TILE_A 4096       // edges per phase-A workgroup (16/thread)

static inline size_t align_up(size_t v, size_t a) { return (v + a - 1) / a * a; }

// ---- init: bucket cursors + zero scalar pooled ------------------------------
__global__ void k_init(int* __restrict__ cursor, float* __restrict__ pooledS, int nb) {
    int i = blockIdx.x * blockDim.x + threadIdx.x;
    if (i < nb) cursor[i] = i * CAP;
    if (i < N_GRAPHS) pooledS[i] = 0.f;
}

// ---- Phase A: partition edges into dst-range buckets ------------------------
__global__ void k_bucketA(const int* __restrict__ src, const int* __restrict__ dst,
                          int* __restrict__ cursor, int* __restrict__ bucketBuf,
                          int ne, int nb) {
    __shared__ int hist[512];
    __shared__ int base[512];
    for (int i = threadIdx.x; i < nb; i += 256) hist[i] = 0;
    __syncthreads();
    int t0 = blockIdx.x * TILE_A + threadIdx.x;
    int s[16], d[16];
#pragma unroll
    for (int k = 0; k < 16; ++k) {
        int e = t0 + k * 256;
        if (e < ne) {
            s[k] = __builtin_nontemporal_load(src + e);
            d[k] = __builtin_nontemporal_load(dst + e);
        } else { s[k] = 0; d[k] = -1; }
    }
#pragma unroll
    for (int k = 0; k < 16; ++k)
        if (d[k] >= 0) atomicAdd(&hist[d[k] >> 8], 1);
    __syncthreads();
    for (int i = threadIdx.x; i < nb; i += 256)
        base[i] = (hist[i] > 0) ? atomicAdd(&cursor[i], hist[i]) : 0;
    __syncthreads();
#pragma unroll
    for (int k = 0; k < 16; ++k)
        if (d[k] >= 0) {
            int b = d[k] >> 8;
            int slot = atomicAdd(&base[b], 1);
            int lim = b * CAP + (CAP - 1);
            if (slot > lim) slot = lim;   // overflow guard (never expected)
            bucketBuf[slot] = (s[k] << 8) | (d[k] & 255);
        }
}

// ---- Phase B: counting sort -> csr + pk + dinv + prescaled fp16 x [n][16] ---
__global__ void k_bucketB(const int* __restrict__ cursor, const int* __restrict__ bucketBuf,
                          const float* __restrict__ x,
                          int* __restrict__ csr, unsigned* __restrict__ pk,
                          float* __restrict__ dinv, __half* __restrict__ xh, int n) {
    int b = blockIdx.x;
    int beg = b * CAP;
    int cnt = cursor[b] - beg;
    if (cnt > CAP) cnt = CAP;
    __shared__ int hist[256];
    __shared__ int scan[256];
    hist[threadIdx.x] = 0;
    __syncthreads();
    for (int j = threadIdx.x; j < cnt; j += 256)
        atomicAdd(&hist[__builtin_nontemporal_load(bucketBuf + beg + j) & 255], 1);
    __syncthreads();
    int v = hist[threadIdx.x];
    scan[threadIdx.x] = v;
    __syncthreads();
    for (int off = 1; off < 256; off <<= 1) {
        int t = (threadIdx.x >= off) ? scan[threadIdx.x - off] : 0;
        __syncthreads();
        scan[threadIdx.x] += t;
        __syncthreads();
    }
    int excl = scan[threadIdx.x] - v;
    int node = (b << 8) + threadIdx.x;
    if (node < n) {
        pk[node] = (unsigned)(beg + excl) | ((unsigned)v << 22);
        float dd = (float)v + 1.0f;
        float dv = 1.0f / sqrtf(dd);
        dinv[node] = dv;
        // fused pad: xh[node] = dv * x[node], 10 feats zero-padded to 16 (fp16)
        const float* row = x + (size_t)node * 10;
        float vals[16];
#pragma unroll
        for (int k = 0; k < 10; ++k) vals[k] = row[k] * dv;
#pragma unroll
        for (int k = 10; k < 16; ++k) vals[k] = 0.f;
        __half2 out[8];
#pragma unroll
        for (int i = 0; i < 8; ++i) out[i] = __floats2half2_rn(vals[2 * i], vals[2 * i + 1]);
        *(float4*)(xh + (size_t)node * 16)     = *(float4*)(out);
        *(float4*)(xh + (size_t)node * 16 + 8) = *(float4*)(out + 4);
    }
    __syncthreads();
    hist[threadIdx.x] = excl;   // reuse as scatter cursor
    __syncthreads();
    for (int j = threadIdx.x; j < cnt; j += 256) {
        int pkk = __builtin_nontemporal_load(bucketBuf + beg + j);
        int slot = atomicAdd(&hist[pkk & 255], 1);
        csr[beg + slot] = pkk >> 8;
    }
}

// 8 fp16 feats -> add into a0..a7
#define CVT8ADD(qq) do { \
    const __half2* hp_ = (const __half2*)&(qq); \
    float2 f0_ = __half22float2(hp_[0]); \
    float2 f1_ = __half22float2(hp_[1]); \
    float2 f2_ = __half22float2(hp_[2]); \
    float2 f3_ = __half22float2(hp_[3]); \
    a0 += f0_.x; a1 += f0_.y; a2 += f1_.x; a3 += f1_.y; \
    a4 += f2_.x; a5 += f2_.y; a6 += f3_.x; a7 += f3_.y; } while (0)

#define RED8(mask) do { \
    a0 += __shfl_xor(a0, mask); a1 += __shfl_xor(a1, mask); \
    a2 += __shfl_xor(a2, mask); a3 += __shfl_xor(a3, mask); \
    a4 += __shfl_xor(a4, mask); a5 += __shfl_xor(a5, mask); \
    a6 += __shfl_xor(a6, mask); a7 += __shfl_xor(a7, mask); } while (0)

// 4-edge-unrolled gather loop over a table of 32 B fp16 rows
// lane layout: half = lane&1; edge-slot q = (lane>>1)&3; node slot = lane>>3
#define GATHER_LOOP16(tbl) do { \
    int j = beg + q; \
    for (; j + 12 < end; j += 16) { \
        int sA = __builtin_nontemporal_load(csr + j); \
        int sB = __builtin_nontemporal_load(csr + j + 4); \
        int sC = __builtin_nontemporal_load(csr + j + 8); \
        int sD = __builtin_nontemporal_load(csr + j + 12); \
        float4 qA = *(const float4*)((tbl) + (size_t)sA * 16 + half * 8); \
        float4 qB = *(const float4*)((tbl) + (size_t)sB * 16 + half * 8); \
        float4 qC = *(const float4*)((tbl) + (size_t)sC * 16 + half * 8); \
        float4 qD = *(const float4*)((tbl) + (size_t)sD * 16 + half * 8); \
        CVT8ADD(qA); CVT8ADD(qB); CVT8ADD(qC); CVT8ADD(qD); \
    } \
    for (; j < end; j += 4) { \
        int s = __builtin_nontemporal_load(csr + j); \
        float4 qq = *(const float4*)((tbl) + (size_t)s * 16 + half * 8); \
        CVT8ADD(qq); \
    } } while (0)

// ---- fused gather1 + MLP: mh = fp16(dinv * (relu(z@W1+b1)@W2))  [n][32] -----
// 64 nodes per 512-thread block; z only in LDS; x table fp16 [n][16] (3.2 MB).
__global__ void k_g1lin(const int* __restrict__ csr, const unsigned* __restrict__ pk,
                        const float* __restrict__ dinv, const __half* __restrict__ xh,
                        const float* __restrict__ W1, const float* __restrict__ b1,
                        const float* __restrict__ W2, __half* __restrict__ mh, int n) {
    __shared__ __align__(16) float W1s[640];
    __shared__ __align__(16) float W2s[2048];
    __shared__ __align__(16) float zt[64 * 17];
    __shared__ __align__(16) float hs[64 * 65];
    for (int i = threadIdx.x; i < 640; i += 512)  W1s[i] = W1[i];
    for (int i = threadIdx.x; i < 2048; i += 512) W2s[i] = W2[i];

    int half = threadIdx.x & 1;
    int q = (threadIdx.x >> 1) & 3;
    int slot = threadIdx.x >> 3;                 // 0..63
    int v = blockIdx.x * 64 + slot;
    bool valid = (v < n);
    float a0=0.f,a1=0.f,a2=0.f,a3=0.f,a4=0.f,a5=0.f,a6=0.f,a7=0.f;
    if (valid) {
        unsigned p = pk[v];
        int beg = (int)(p & 0x3FFFFFu), end = beg + (int)(p >> 22);
        GATHER_LOOP16(xh);
    }
    RED8(2); RED8(4);
    if (q == 0) {
        float o[8] = {0.f,0.f,0.f,0.f,0.f,0.f,0.f,0.f};
        if (valid) {
            float dv = dinv[v];
            float4 qs = *(const float4*)(xh + (size_t)v * 16 + half * 8);
            const __half2* sp = (const __half2*)&qs;
            float2 s0 = __half22float2(sp[0]), s1 = __half22float2(sp[1]);
            float2 s2 = __half22float2(sp[2]), s3 = __half22float2(sp[3]);
            o[0] = (a0 + s0.x) * dv; o[1] = (a1 + s0.y) * dv;
            o[2] = (a2 + s1.x) * dv; o[3] = (a3 + s1.y) * dv;
            o[4] = (a4 + s2.x) * dv; o[5] = (a5 + s2.y) * dv;
            o[6] = (a6 + s3.x) * dv; o[7] = (a7 + s3.y) * dv;
        }
        float* zr = zt + slot * 17 + half * 8;
#pragma unroll
        for (int i = 0; i < 8; ++i) zr[i] = o[i];
    }
    __syncthreads();
    // h1 phase: node = tid&63, w = tid>>6 computes 8 consecutive feats via
    // broadcast b128 W1 reads (all 64 lanes same address).
    {
        int node = threadIdx.x & 63, w = threadIdx.x >> 6;
        float zreg[10];
#pragma unroll
        for (int k = 0; k < 10; ++k) zreg[k] = zt[node * 17 + k];
        float acc[8];
        {
            float4 bva = *(const float4*)(b1 + w * 8);
            float4 bvb = *(const float4*)(b1 + w * 8 + 4);
            acc[0] = bva.x; acc[1] = bva.y; acc[2] = bva.z; acc[3] = bva.w;
            acc[4] = bvb.x; acc[5] = bvb.y; acc[6] = bvb.z; acc[7] = bvb.w;
        }
        const float4* W1v = (const float4*)W1s;
#pragma unroll
        for (int k = 0; k < 10; ++k) {
            float zk = zreg[k];
            float4 wa = W1v[k * 16 + w * 2];
            float4 wb = W1v[k * 16 + w * 2 + 1];
            acc[0] += zk * wa.x; acc[1] += zk * wa.y;
            acc[2] += zk * wa.z; acc[3] += zk * wa.w;
            acc[4] += zk * wb.x; acc[5] += zk * wb.y;
            acc[6] += zk * wb.z; acc[7] += zk * wb.w;
        }
        float* hr = hs + node * 65 + w * 8;
#pragma unroll
        for (int i = 0; i < 8; ++i) hr[i] = fmaxf(acc[i], 0.f);
    }
    __syncthreads();
    // m phase (register-blocked): node = tid>>3, 4 consecutive outputs og*4..+3.
    // Per f: 1 broadcast hs read + 1 broadcast b128 W2 read + 4 FMA.
    {
        int node = threadIdx.x >> 3, og = threadIdx.x & 7;
        int vv = blockIdx.x * 64 + node;
        if (vv < n) {
            float s0 = 0.f, s1 = 0.f, s2 = 0.f, s3 = 0.f;
            const float4* W2v = (const float4*)W2s;   // [f][32] -> f*8 float4s
            const float* hr = hs + node * 65;
#pragma unroll
            for (int f = 0; f < 64; ++f) {
                float hv = hr[f];
                float4 w4 = W2v[f * 8 + og];
                s0 += hv * w4.x; s1 += hv * w4.y;
                s2 += hv * w4.z; s3 += hv * w4.w;
            }
            float dv = dinv[vv];
            __half2 p0 = __floats2half2_rn(s0 * dv, s1 * dv);
            __half2 p1 = __floats2half2_rn(s2 * dv, s3 * dv);
            __half2* outp = (__half2*)(mh + (size_t)vv * 32 + og * 4);
            outp[0] = p0; outp[1] = p1;
        }
    }
}

// ---- gather2 single pass (32 fp16 feats, 64 B rows) + relu + FC + pool ------
// lane layout: quarter = lane&3; edge-slot q = (lane>>2)&1; node slot = lane>>3
__global__ void k_gath2(const int* __restrict__ csr, const unsigned* __restrict__ pk,
                        const float* __restrict__ dinv, const __half* __restrict__ mh,
                        const float* __restrict__ b2, const float* __restrict__ Wfc,
                        const int* __restrict__ batch, float* __restrict__ pooledS, int n) {
    int quarter = threadIdx.x & 3;
    int q = (threadIdx.x >> 2) & 1;
    int v = blockIdx.x * 32 + (threadIdx.x >> 3);
    bool valid = (v < n);
    float a0=0.f,a1=0.f,a2=0.f,a3=0.f,a4=0.f,a5=0.f,a6=0.f,a7=0.f;
    int b = -1;
    if (valid) {
        unsigned p = pk[v];
        int beg = (int)(p & 0x3FFFFFu), end = beg + (int)(p >> 22);
        int j = beg + q;
        for (; j + 6 < end; j += 8) {
            int sA = __builtin_nontemporal_load(csr + j);
            int sB = __builtin_nontemporal_load(csr + j + 2);
            int sC = __builtin_nontemporal_load(csr + j + 4);
            int sD = __builtin_nontemporal_load(csr + j + 6);
            float4 qA = *(const float4*)(mh + (size_t)sA * 32 + quarter * 8);
            float4 qB = *(const float4*)(mh + (size_t)sB * 32 + quarter * 8);
            float4 qC = *(const float4*)(mh + (size_t)sC * 32 + quarter * 8);
            float4 qD = *(const float4*)(mh + (size_t)sD * 32 + quarter * 8);
            CVT8ADD(qA); CVT8ADD(qB); CVT8ADD(qC); CVT8ADD(qD);
        }
        for (; j < end; j += 2) {
            int s = __builtin_nontemporal_load(csr + j);
            float4 qq = *(const float4*)(mh + (size_t)s * 32 + quarter * 8);
            CVT8ADD(qq);
        }
        b = batch[v];
    }
    RED8(4);   // fold edge-slot q
    float part = 0.f;
    if (valid) {
        float dv = dinv[v];
        float4 qs = *(const float4*)(mh + (size_t)v * 32 + quarter * 8);
        const __half2* sp = (const __half2*)&qs;
        float2 s0 = __half22float2(sp[0]), s1 = __half22float2(sp[1]);
        float2 s2 = __half22float2(sp[2]), s3 = __half22float2(sp[3]);
        const float* bb = b2 + quarter * 8;
        const float* wf = Wfc + quarter * 8;
        part  = fmaxf((a0 + s0.x) * dv + bb[0], 0.f) * wf[0];
        part += fmaxf((a1 + s0.y) * dv + bb[1], 0.f) * wf[1];
        part += fmaxf((a2 + s1.x) * dv + bb[2], 0.f) * wf[2];
        part += fmaxf((a3 + s1.y) * dv + bb[3], 0.f) * wf[3];
        part += fmaxf((a4 + s2.x) * dv + bb[4], 0.f) * wf[4];
        part += fmaxf((a5 + s2.y) * dv + bb[5], 0.f) * wf[5];
        part += fmaxf((a6 + s3.x) * dv + bb[6], 0.f) * wf[6];
        part += fmaxf((a7 + s3.y) * dv + bb[7], 0.f) * wf[7];
    }
    // fold quarters (masks 1,2): every lane of the node now holds t[v]
    part += __shfl_xor(part, 1);
    part += __shfl_xor(part, 2);
    int b0 = __shfl(b, 0);
    bool uni = __all(!valid || b == b0);
    if (uni) {
        // butterfly over node slots: lane 0's partner set {0,8,...,56} counts
        // each node's t exactly once.
        part += __shfl_xor(part, 8);
        part += __shfl_xor(part, 16);
        part += __shfl_xor(part, 32);
        if ((threadIdx.x & 63) == 0 && b0 >= 0) {
            atomicAdd(pooledS + b0, part);
        }
    } else if (valid && (threadIdx.x & 7) == 0) {
        atomicAdd(pooledS + b, part);
    }
}

// ---- out[g] = sigmoid(pooledS[g] + bfc) -------------------------------------
__global__ void k_fc(const float* __restrict__ pooledS, const float* __restrict__ bfc,
                     float* __restrict__ out) {
    int g = blockIdx.x * blockDim.x + threadIdx.x;
    if (g < N_GRAPHS) out[g] = 1.0f / (1.0f + expf(-(pooledS[g] + bfc[0])));
}

extern "C" void kernel_launch(void* const* d_in, const int* in_sizes, int n_in,
                              void* d_out, int out_size, void* d_ws, size_t ws_size,
                              hipStream_t stream) {
    const int n  = in_sizes[0] / 10;   // 100000 nodes
    const int ne = in_sizes[1] / 2;    // 1600000 edges
    const int nb = (n + 255) >> 8;     // 391 buckets

    const float* x     = (const float*)d_in[0];
    const int*   ei    = (const int*)d_in[1];
    const int*   batch = (const int*)d_in[2];
    const float* W1    = (const float*)d_in[3];
    const float* b1    = (const float*)d_in[4];
    const float* W2    = (const float*)d_in[5];
    const float* b2    = (const float*)d_in[6];
    const float* Wfc   = (const float*)d_in[7];
    const float* bfc   = (const float*)d_in[8];
    const int* srcp = ei;
    const int* dstp = ei + ne;

    // workspace layout
    char* base = (char*)d_ws;
    size_t off = 0;
    auto take = [&](size_t bytes) { void* p = base + off; off = align_up(off + bytes, 16); return p; };
    int*      cursor    = (int*)     take((size_t)nb * 4);
    int*      bucketBuf = (int*)     take((size_t)nb * CAP * 4);
    int*      csr       = (int*)     take((size_t)nb * CAP * 4);
    unsigned* pk        = (unsigned*)take((size_t)n * 4);
    float*    dinv      = (float*)   take((size_t)n * 4);
    __half*   xh        = (__half*)  take((size_t)n * 16 * 2);
    __half*   mh        = (__half*)  take((size_t)n * 32 * 2);   // [n][32]
    float*    pooledS   = (float*)   take((size_t)N_GRAPHS * 4);

    k_init   <<<4, 256, 0, stream>>>(cursor, pooledS, nb);
    k_bucketA<<<(ne + TILE_A - 1) / TILE_A, 256, 0, stream>>>(srcp, dstp, cursor, bucketBuf, ne, nb);
    k_bucketB<<<nb, 256, 0, stream>>>(cursor, bucketBuf, x, csr, pk, dinv, xh, n);
    k_g1lin  <<<(n + 63) / 64, 512, 0, stream>>>(csr, pk, dinv, xh, W1, b1, W2, mh, n);
    k_gath2  <<<(n + 31) / 32, 256, 0, stream>>>(csr, pk, dinv, mh,
                                                 b2, Wfc, batch, pooledS, n);
    k_fc     <<<2, 256, 0, stream>>>(pooledS, bfc, (float*)d_out);
}